// Round 6
// baseline (1257.961 us; speedup 1.0000x reference)
//
#include <hip/hip_runtime.h>

#define NT 131072
#define ED 128
#define KCB 1024
#define NQ 4

#define MT 128                 // tokens per block
#define NBLK (NT / MT)         // 1024 blocks
#define NCH 64                 // codes per chunk
#define NCHUNKS (KCB / NCH)    // 16
#define PAIR_CAP 1024
#define MARGIN 1.5e-3f

typedef __attribute__((ext_vector_type(8))) short bf16x8;
typedef __attribute__((ext_vector_type(4))) float f32x4;

// ---- bf16 round-to-nearest-even, returns low 16 bits ----
__device__ __forceinline__ unsigned bf16rne(float f) {
    unsigned u = __float_as_uint(f);
    u += 0x7fffu + ((u >> 16) & 1u);
    return u >> 16;
}
__device__ __forceinline__ unsigned packbf(float a, float b) {
    return bf16rne(a) | (bf16rne(b) << 16);
}
// ---- monotone float->uint (unsigned compare preserves float order) ----
__device__ __forceinline__ unsigned fmono(float f) {
    unsigned u = __float_as_uint(f);
    return (u & 0x80000000u) ? ~u : (u | 0x80000000u);
}

// ---------------------------------------------------------------------------
// prep: cnorm[c] = np.sum(cb*cb, axis=1) fp32 numpy-pairwise (validated r3);
// zero the loss slot.
// ---------------------------------------------------------------------------
__global__ void prep_kernel(const float* __restrict__ cb,
                            float* __restrict__ cnorm,
                            float* __restrict__ loss_slot) {
#pragma clang fp contract(off)
    int c = blockIdx.x * 256 + threadIdx.x;   // 0..4095
    if (blockIdx.x == 0 && threadIdx.x == 0) loss_slot[0] = 0.0f;
    const float* row = cb + (size_t)c * ED;
    float r8[8];
#pragma unroll
    for (int m = 0; m < 8; ++m) { float v = row[m]; r8[m] = v * v; }
    for (int i = 8; i < ED; i += 8) {
#pragma unroll
        for (int m = 0; m < 8; ++m) {
            float v = row[i + m];
            float p = v * v;
            r8[m] = r8[m] + p;
        }
    }
    cnorm[c] = ((r8[0] + r8[1]) + (r8[2] + r8[3]))
             + ((r8[4] + r8[5]) + (r8[6] + r8[7]));
}

// ---------------------------------------------------------------------------
// cvt: pre-convert codebooks to bf16 (same RNE -> bit-identical MFMA inputs)
// into a LINEAR chunk-major image (read directly from L1/L2 by the main
// kernel; no LDS staging, so no swizzle needed).
// Layout: image (q*16+chunk) of 16384 B; within: row*256 + j*16.
// ---------------------------------------------------------------------------
__global__ void cvt_kernel(const float* __restrict__ cb,
                           unsigned char* __restrict__ cbb) {
#pragma clang fp contract(off)
    int id = blockIdx.x * 256 + threadIdx.x;        // 0..65535
    int rg = id >> 4;                               // global code row 0..4095
    int j  = id & 15;                               // 16B block within row
    const float* src = cb + (size_t)rg * ED + j * 8;
    float4 a = *(const float4*)(src);
    float4 b = *(const float4*)(src + 4);
    uint4 w;
    w.x = packbf(a.x, a.y); w.y = packbf(a.z, a.w);
    w.z = packbf(b.x, b.y); w.w = packbf(b.z, b.w);
    size_t dst = ((size_t)(rg >> 6) << 14)          // 16 KiB chunk image
               + (size_t)((rg & 63) << 8)           // row * 256 B
               + (size_t)(j << 4);                  // linear 16B slot
    *(uint4*)(cbb + dst) = w;
}

// ---------------------------------------------------------------------------
// per-element straight-through chain step (validated r3): given r and code val
// q: d1=fl(q-r); qt=fl(r+d1); rn=fl(r-qt)
#define CHAIN4(V, C)                                                     \
    { float d1x = (C).x - (V).x, d1y = (C).y - (V).y,                    \
            d1z = (C).z - (V).z, d1w = (C).w - (V).w;                    \
      float qtx = (V).x + d1x, qty = (V).y + d1y,                        \
            qtz = (V).z + d1z, qtw = (V).w + d1w;                        \
      (V).x = (V).x - qtx; (V).y = (V).y - qty;                          \
      (V).z = (V).z - qtz; (V).w = (V).w - qtw; }

// ---------------------------------------------------------------------------
// one RVQ stage, Q = compile-time stage index. Barrier-light structure:
//  [barrier] resets | per-wave: S(own 32 tokens) -> bfrag -> 16 chunks
//  (NO barriers; codes read direct from L1/L2) | [barrier] rescore
//  [barrier] index write [barrier]
// ---------------------------------------------------------------------------
template<int Q>
__device__ __forceinline__ void run_stage(
    const float* __restrict__ x, const float* __restrict__ cb,
    const float* __restrict__ cnorm, const unsigned char* __restrict__ cbb,
    float* __restrict__ d_out,
    unsigned char* U, unsigned long long* selMin, float* Ss,
    unsigned short* selSh, unsigned* pairList, int* pairCnt,
    int tid, int lane, int wid, int l15, int quad, int t0, unsigned xorT) {
#pragma clang fp contract(off)
    const float* cbq = cb + (size_t)Q * KCB * ED;
    const unsigned char* cbbq = cbb + ((size_t)Q << 18);  // Q*16 images
    const float* cnq = cnorm + Q * KCB;

    if (tid < MT) selMin[tid] = ~0ull;
    if (tid == 0) *pairCnt = 0;
    __syncthreads();   // resets visible; prev stage fully done

    // ---- S (numpy pairwise) + As bf16 (swizzled), residual recomputed
    //      from x + selection history (exact fp32 chain, r3-validated).
    //      WAVE-OWNED: wave w, lanes 0-31 handle tokens w*32..w*32+31;
    //      per-token math identical to the validated tid<128 mapping. ----
    if (lane < 32) {
        int t = (wid << 5) | lane;
        const float* xr = x + (size_t)(t0 + t) * ED;
        const float* hp[Q > 0 ? Q : 1];
#pragma unroll
        for (int p2 = 0; p2 < Q; ++p2)
            hp[p2] = cb + ((size_t)p2 * KCB + (int)selSh[t * NQ + p2]) * ED;
        unsigned char* Aw = U + t * 256;
        unsigned xw = (unsigned)((t & 7) << 4);
        float r8[8];
#pragma unroll
        for (int m = 0; m < 8; ++m) r8[m] = 0.f;
#pragma unroll 4
        for (int i = 0; i < 32; ++i) {
            float4 v = *(const float4*)(xr + (i << 2));
#pragma unroll
            for (int p2 = 0; p2 < Q; ++p2) {
                float4 c = *(const float4*)(hp[p2] + (i << 2));
                CHAIN4(v, c)
            }
            // pack to As (bf16 RNE), 16B-slot XOR swizzle
            uint2 w2;
            w2.x = packbf(v.x, v.y); w2.y = packbf(v.z, v.w);
            *(uint2*)(Aw + (((((unsigned)(i >> 1)) << 4) ^ xw)
                            | ((unsigned)(i & 1) << 3))) = w2;
            // numpy 8-acc squares: k=4i+j -> m=(4i+j)&7
            int base = (i & 1) << 2;
            float px = v.x * v.x, py = v.y * v.y,
                  pz = v.z * v.z, pw = v.w * v.w;
            r8[base + 0] = r8[base + 0] + px;
            r8[base + 1] = r8[base + 1] + py;
            r8[base + 2] = r8[base + 2] + pz;
            r8[base + 3] = r8[base + 3] + pw;
        }
        Ss[t] = ((r8[0] + r8[1]) + (r8[2] + r8[3]))
              + ((r8[4] + r8[5]) + (r8[6] + r8[7]));
    }
    // no barrier: As/bfrag are wave-private (cross-lane within wave only;
    // compiler's lgkmcnt ordering covers LDS write->read in program order)

    // ---- load token (B-operand) fragments: own tokens only ----
    bf16x8 bfrag[2][4];
#pragma unroll
    for (int tt = 0; tt < 2; ++tt)
#pragma unroll
        for (int ks = 0; ks < 4; ++ks) {
            int tok = wid * 32 + tt * 16 + l15;
            bfrag[tt][ks] = *(const bf16x8*)(U + tok * 256 +
                (((unsigned)(ks * 64 + quad * 16)) ^ xorT));
        }

    // ---- chunk loop: NO barriers, NO LDS staging. Code fragments are
    //      read directly from the linear bf16 image (L1/L2-hot: 1 MB
    //      shared by all 1024 blocks). Waves run fully independently. ----
    float rmin[2] = {1e30f, 1e30f};   // per-token running min (wave-private)
    for (int cc = 0; cc < NCHUNKS; ++cc) {
        const unsigned char* Cb = cbbq + ((size_t)cc << 14);

        // cnorm fragments (L1-hot, hidable)
        f32x4 cnr[4];
#pragma unroll
        for (int ct = 0; ct < 4; ++ct)
            cnr[ct] = *(const f32x4*)(cnq + cc * NCH + ct * 16 + quad * 4);

        // MFMA: D[code][token] over 64 codes x 32 tokens per wave
        f32x4 acc[4][2];
#pragma unroll
        for (int ct = 0; ct < 4; ++ct)
#pragma unroll
            for (int tt = 0; tt < 2; ++tt)
                acc[ct][tt] = (f32x4){0.f, 0.f, 0.f, 0.f};
#pragma unroll
        for (int ks = 0; ks < 4; ++ks) {
            bf16x8 afr[4];
#pragma unroll
            for (int ct = 0; ct < 4; ++ct)
                afr[ct] = *(const bf16x8*)(Cb + (ct * 16 + l15) * 256
                                              + ks * 64 + quad * 16);
#pragma unroll
            for (int ct = 0; ct < 4; ++ct)
#pragma unroll
                for (int tt = 0; tt < 2; ++tt)
                    acc[ct][tt] = __builtin_amdgcn_mfma_f32_16x16x32_bf16(
                        afr[ct], bfrag[tt][ks], acc[ct][tt], 0, 0, 0);
        }

        // scores e = cn - 2*M~ (approx; exact handled by rescore) + min
        float tmin[2] = {1e30f, 1e30f};
#pragma unroll
        for (int ct = 0; ct < 4; ++ct) {
            f32x4 cn4 = cnr[ct];
#pragma unroll
            for (int tt = 0; tt < 2; ++tt)
#pragma unroll
                for (int r2 = 0; r2 < 4; ++r2) {
                    float m2 = acc[ct][tt][r2];
                    float e = cn4[r2] - (m2 + m2);
                    acc[ct][tt][r2] = e;
                    tmin[tt] = fminf(tmin[tt], e);
                }
        }
#pragma unroll
        for (int tt = 0; tt < 2; ++tt) {
            float v = tmin[tt];
            v = fminf(v, __shfl_xor(v, 16, 64));
            v = fminf(v, __shfl_xor(v, 32, 64));
            rmin[tt] = fminf(rmin[tt], v);   // all lanes hold token min
        }

        // candidate pass for THIS chunk (threshold incl. own chunk)
#pragma unroll
        for (int tt = 0; tt < 2; ++tt) {
            int token = wid * 32 + tt * 16 + l15;
            float th = rmin[tt] + MARGIN;
#pragma unroll
            for (int ct = 0; ct < 4; ++ct)
#pragma unroll
                for (int r2 = 0; r2 < 4; ++r2) {
                    float e = acc[ct][tt][r2];
                    if (e <= th) {
                        int code = cc * NCH + ct * 16 + quad * 4 + r2;
                        int pos = atomicAdd(pairCnt, 1);
                        if (pos < PAIR_CAP)
                            pairList[pos] =
                                ((unsigned)token << 10) | (unsigned)code;
                    }
                }
        }
    }
    __syncthreads();   // all waves' pushes + Ss visible

    // ---- exact rescore of candidates (bit-identical to r3 math) ----
    {
        int npair = *pairCnt < PAIR_CAP ? *pairCnt : PAIR_CAP;
        for (int p = tid; p < npair; p += 256) {
            unsigned pk = pairList[p];
            int t = (pk >> 10) & 127, code = pk & 1023;
            const float* xr = x + (size_t)(t0 + t) * ED;
            const float* cr = cbq + (size_t)code * ED;
            const float* hp[Q > 0 ? Q : 1];
#pragma unroll
            for (int p2 = 0; p2 < Q; ++p2)
                hp[p2] = cb + ((size_t)p2 * KCB + (int)selSh[t * NQ + p2]) * ED;
            float M = 0.f;
#pragma unroll 4
            for (int k = 0; k < ED; k += 4) {
                float4 v = *(const float4*)(xr + k);
#pragma unroll
                for (int p2 = 0; p2 < Q; ++p2) {
                    float4 c = *(const float4*)(hp[p2] + k);
                    CHAIN4(v, c)
                }
                float4 cv = *(const float4*)(cr + k);
                M = fmaf(v.x, cv.x, M); M = fmaf(v.y, cv.y, M);
                M = fmaf(v.z, cv.z, M); M = fmaf(v.w, cv.w, M);
            }
            float t1 = Ss[t] - (M + M);             // rounded (contract off)
            float dd = t1 + cnorm[Q * KCB + code];  // rounded
            unsigned long long key =
                ((unsigned long long)fmono(dd) << 10) | (unsigned)code;
            unsigned long long old = selMin[t];
            while (key < old) {
                unsigned long long assumed = old;
                old = atomicCAS(&selMin[t], assumed, key);
                if (old == assumed) break;
            }
        }
    }
    __syncthreads();

    if (tid < MT) {
        int code = (int)(selMin[tid] & 1023ull);
        selSh[tid * NQ + Q] = (unsigned short)code;
        d_out[(size_t)NT * ED + 1 + (size_t)(t0 + tid) * NQ + Q] = (float)code;
    }
    __syncthreads();   // selSh visible to next stage's S-phase
}

// ---------------------------------------------------------------------------
// main fused MFMA RVQ kernel
// out: [0, NT*ED) x_q | [NT*ED] loss | [NT*ED+1 ...) indices (as f32)
// LDS ~38.6 KB; 4 barriers/stage (was ~37). Waves run independently
// through S + chunk loop; TLP does the latency hiding.
// ---------------------------------------------------------------------------
__global__ __launch_bounds__(256, 3) void rvq_mfma(const float* __restrict__ x,
                                                   const float* __restrict__ cb,
                                                   const float* __restrict__ cnorm,
                                                   const unsigned char* __restrict__ cbb,
                                                   float* __restrict__ d_out) {
#pragma clang fp contract(off)
    // U: As only (128 tokens x 256 B, swizzled, wave-private quarters)
    __shared__ __align__(16) unsigned char U[32768];
    __shared__ unsigned long long selMin[MT];
    __shared__ float    Ss[MT];
    __shared__ unsigned short selSh[MT * NQ];
    __shared__ unsigned pairList[PAIR_CAP];
    __shared__ int      pairCnt;
    __shared__ double   lossW[4];

    const int tid  = threadIdx.x;
    const int lane = tid & 63;
    const int wid  = tid >> 6;     // wave 0..3 -> tokens [wid*32, wid*32+32)
    const int l15  = lane & 15;
    const int quad = lane >> 4;
    const int t0   = blockIdx.x * MT;
    const unsigned xorT = (unsigned)((l15 & 7) << 4);

    run_stage<0>(x, cb, cnorm, cbb, d_out, U, selMin, Ss, selSh,
                 pairList, &pairCnt, tid, lane, wid, l15, quad, t0, xorT);
    run_stage<1>(x, cb, cnorm, cbb, d_out, U, selMin, Ss, selSh,
                 pairList, &pairCnt, tid, lane, wid, l15, quad, t0, xorT);
    run_stage<2>(x, cb, cnorm, cbb, d_out, U, selMin, Ss, selSh,
                 pairList, &pairCnt, tid, lane, wid, l15, quad, t0, xorT);
    run_stage<3>(x, cb, cnorm, cbb, d_out, U, selMin, Ss, selSh,
                 pairList, &pairCnt, tid, lane, wid, l15, quad, t0, xorT);

    // ---- epilogue: x_q = x - r4 (exact chain), loss = sum ||r_1..4||^2 ----
    double lossTot = 0.0;
    if (tid < MT) {
        int t = tid;
        const float* xr = x + (size_t)(t0 + t) * ED;
        const float* hp[4];
#pragma unroll
        for (int p2 = 0; p2 < NQ; ++p2)
            hp[p2] = cb + ((size_t)p2 * KCB + (int)selSh[t * NQ + p2]) * ED;
        double lo = 0.0;
#pragma unroll 4
        for (int k = 0; k < ED; k += 4) {
            float4 v = *(const float4*)(xr + k);
            float4 o = v;
#pragma unroll
            for (int p2 = 0; p2 < NQ; ++p2) {
                float4 c = *(const float4*)(hp[p2] + k);
                CHAIN4(v, c)
                lo += (double)v.x * v.x + (double)v.y * v.y
                    + (double)v.z * v.z + (double)v.w * v.w;
            }
            float4 xq;
            xq.x = o.x - v.x; xq.y = o.y - v.y;
            xq.z = o.z - v.z; xq.w = o.w - v.w;
            *(float4*)(d_out + (size_t)(t0 + t) * ED + k) = xq;
        }
        lossTot = lo;
    }

    // loss reduce: wave shuffle -> LDS -> one atomic per block
    double l = lossTot;
#pragma unroll
    for (int off = 32; off > 0; off >>= 1) l += __shfl_down(l, off, 64);
    if ((tid & 63) == 0) lossW[tid >> 6] = l;
    __syncthreads();
    if (tid == 0) {
        double s = lossW[0] + lossW[1] + lossW[2] + lossW[3];
        // mean_loss = BETA/(4*N*E) * sum_q ||r_{q+1}||^2
        atomicAdd(d_out + (size_t)NT * ED, (float)(s * (0.25 / (4.0 * (double)NT * ED))));
    }
}

// ---------------------------------------------------------------------------
// workspace layout: [0,16KB) cnorm | [16KB, 16KB+1MB) bf16 linear codebook
// ---------------------------------------------------------------------------
extern "C" void kernel_launch(void* const* d_in, const int* in_sizes, int n_in,
                              void* d_out, int out_size, void* d_ws, size_t ws_size,
                              hipStream_t stream) {
    const float* x  = (const float*)d_in[0];
    const float* cb = (const float*)d_in[1];
    float* out   = (float*)d_out;
    float* cnorm = (float*)d_ws;                          // 4096 floats
    unsigned char* cbb = (unsigned char*)d_ws + 16384;    // 1 MiB bf16 images

    prep_kernel<<<16, 256, 0, stream>>>(cb, cnorm, out + (size_t)NT * ED);
    cvt_kernel<<<256, 256, 0, stream>>>(cb, cbb);
    rvq_mfma<<<NBLK, 256, 0, stream>>>(x, cb, cnorm, cbb, out);
}

// Round 7
// 1179.367 us; speedup vs baseline: 1.0666x; 1.0666x over previous
//
#include <hip/hip_runtime.h>

#define NT 131072
#define ED 128
#define KCB 1024
#define NQ 4

#define MT 128                 // tokens per select-block
#define NBLK (NT / MT)         // 1024 blocks
#define NCH 64                 // codes per chunk
#define NCHUNKS (KCB / NCH)    // 16
#define PAIR_CAP 1024
#define MARGIN 1.5e-3f

#define TRL 16384              // trailer (cnorm slice) offset inside a Bs buf
#define BUFSZ 16640            // 16 KB codes + 256 B cnorm trailer

typedef __attribute__((ext_vector_type(8))) short bf16x8;
typedef __attribute__((ext_vector_type(4))) float f32x4;

#define ASG __attribute__((address_space(1)))
#define ASL __attribute__((address_space(3)))
#define GLOAD_LDS16(g, l) \
    __builtin_amdgcn_global_load_lds((const ASG void*)(g), (ASL void*)(l), 16, 0, 0)

// ---- bf16 round-to-nearest-even, returns low 16 bits ----
__device__ __forceinline__ unsigned bf16rne(float f) {
    unsigned u = __float_as_uint(f);
    u += 0x7fffu + ((u >> 16) & 1u);
    return u >> 16;
}
__device__ __forceinline__ unsigned packbf(float a, float b) {
    return bf16rne(a) | (bf16rne(b) << 16);
}
// ---- monotone float->uint (unsigned compare preserves float order) ----
__device__ __forceinline__ unsigned fmono(float f) {
    unsigned u = __float_as_uint(f);
    return (u & 0x80000000u) ? ~u : (u | 0x80000000u);
}

// ---------------------------------------------------------------------------
// prep: cnorm[c] = np.sum(cb*cb, axis=1) fp32 numpy-pairwise (validated r3);
// zero the loss slot.
// ---------------------------------------------------------------------------
__global__ void prep_kernel(const float* __restrict__ cb,
                            float* __restrict__ cnorm,
                            float* __restrict__ loss_slot) {
#pragma clang fp contract(off)
    int c = blockIdx.x * 256 + threadIdx.x;   // 0..4095
    if (blockIdx.x == 0 && threadIdx.x == 0) loss_slot[0] = 0.0f;
    const float* row = cb + (size_t)c * ED;
    float r8[8];
#pragma unroll
    for (int m = 0; m < 8; ++m) { float v = row[m]; r8[m] = v * v; }
    for (int i = 8; i < ED; i += 8) {
#pragma unroll
        for (int m = 0; m < 8; ++m) {
            float v = row[i + m];
            float p = v * v;
            r8[m] = r8[m] + p;
        }
    }
    cnorm[c] = ((r8[0] + r8[1]) + (r8[2] + r8[3]))
             + ((r8[4] + r8[5]) + (r8[6] + r8[7]));
}

// ---------------------------------------------------------------------------
// cvt: codebooks -> bf16 swizzled chunk-linear image (r5-validated layout)
// for pure global_load_lds staging in the select kernel.
// Layout: image (q*16+chunk) of 16384 B; within: row*256 + ((j^(row&7))<<4).
// ---------------------------------------------------------------------------
__global__ void cvt_kernel(const float* __restrict__ cb,
                           unsigned char* __restrict__ cbb) {
#pragma clang fp contract(off)
    int id = blockIdx.x * 256 + threadIdx.x;        // 0..65535
    int rg = id >> 4;                               // global code row 0..4095
    int j  = id & 15;                               // 16B block within row
    const float* src = cb + (size_t)rg * ED + j * 8;
    float4 a = *(const float4*)(src);
    float4 b = *(const float4*)(src + 4);
    uint4 w;
    w.x = packbf(a.x, a.y); w.y = packbf(a.z, a.w);
    w.z = packbf(b.x, b.y); w.w = packbf(b.z, b.w);
    size_t dst = ((size_t)(rg >> 6) << 14)          // 16 KiB chunk image
               + (size_t)((rg & 63) << 8)           // row * 256 B
               + (size_t)((j ^ (rg & 7)) << 4);     // swizzled 16B slot
    *(uint4*)(cbb + dst) = w;
}

// ---------------------------------------------------------------------------
// per-element straight-through chain step (validated r3): given r and code val
// q: d1=fl(q-r); qt=fl(r+d1); rn=fl(r-qt)
#define CHAIN4(V, C)                                                     \
    { float d1x = (C).x - (V).x, d1y = (C).y - (V).y,                    \
            d1z = (C).z - (V).z, d1w = (C).w - (V).w;                    \
      float qtx = (V).x + d1x, qty = (V).y + d1y,                        \
            qtz = (V).z + d1z, qtw = (V).w + d1w;                        \
      (V).x = (V).x - qtx; (V).y = (V).y - qty;                          \
      (V).z = (V).z - qtz; (V).w = (V).w - qtw; }

// ===========================================================================
// SPLIT PATH (used when workspace is large enough)
// ===========================================================================

// ---------------------------------------------------------------------------
// s_kernel<Q>: token-parallel residual/S phase. One thread per token.
// Writes As (bf16, LINEAR 256 B/token) + Ss. Math byte-identical to the
// validated monolith S-phase.
// ---------------------------------------------------------------------------
template<int Q>
__global__ void s_kernel(const float* __restrict__ x,
                         const float* __restrict__ cb,
                         const unsigned short* __restrict__ selG,
                         unsigned char* __restrict__ As,
                         float* __restrict__ SsG) {
#pragma clang fp contract(off)
    int t = blockIdx.x * 256 + threadIdx.x;   // 0..NT-1
    const float* xr = x + (size_t)t * ED;
    const float* hp[Q > 0 ? Q : 1];
#pragma unroll
    for (int p2 = 0; p2 < Q; ++p2)
        hp[p2] = cb + ((size_t)p2 * KCB + (int)selG[t * NQ + p2]) * ED;
    unsigned char* Aw = As + (size_t)t * 256;
    float r8[8];
#pragma unroll
    for (int m = 0; m < 8; ++m) r8[m] = 0.f;
    unsigned w0 = 0, w1 = 0;
#pragma unroll 4
    for (int i = 0; i < 32; ++i) {
        float4 v = *(const float4*)(xr + (i << 2));
#pragma unroll
        for (int p2 = 0; p2 < Q; ++p2) {
            float4 c = *(const float4*)(hp[p2] + (i << 2));
            CHAIN4(v, c)
        }
        if ((i & 1) == 0) {
            w0 = packbf(v.x, v.y); w1 = packbf(v.z, v.w);
        } else {
            uint4 w;
            w.x = w0; w.y = w1;
            w.z = packbf(v.x, v.y); w.w = packbf(v.z, v.w);
            *(uint4*)(Aw + ((i >> 1) << 4)) = w;
        }
        // numpy 8-acc squares: k=4i+j -> m=(4i+j)&7
        int base = (i & 1) << 2;
        float px = v.x * v.x, py = v.y * v.y,
              pz = v.z * v.z, pw = v.w * v.w;
        r8[base + 0] = r8[base + 0] + px;
        r8[base + 1] = r8[base + 1] + py;
        r8[base + 2] = r8[base + 2] + pz;
        r8[base + 3] = r8[base + 3] + pw;
    }
    SsG[t] = ((r8[0] + r8[1]) + (r8[2] + r8[3]))
           + ((r8[4] + r8[5]) + (r8[6] + r8[7]));
}

// ---------------------------------------------------------------------------
// select_kernel<Q>: pure GEMM-screen + exact rescore + selection.
// Chunk loop is the r5-validated DMA + counted-vmcnt pipeline, verbatim.
// bfrag comes straight from the global As image (no LDS As).
// ---------------------------------------------------------------------------
template<int Q>
__global__ __launch_bounds__(256, 3) void select_kernel(
    const float* __restrict__ x, const float* __restrict__ cb,
    const float* __restrict__ cnorm, const unsigned char* __restrict__ cbb,
    const unsigned char* __restrict__ As, const float* __restrict__ SsG,
    unsigned short* __restrict__ selG, float* __restrict__ d_out) {
#pragma clang fp contract(off)
    __shared__ __align__(16) unsigned char U[2 * BUFSZ];   // Bs dbuf + trailers
    __shared__ unsigned long long selMin[MT];
    __shared__ unsigned pairList[PAIR_CAP];
    __shared__ int      pairCnt;

    const int tid  = threadIdx.x;
    const int lane = tid & 63;
    const int wid  = tid >> 6;     // wave 0..3 -> tokens [wid*32, wid*32+32)
    const int l15  = lane & 15;
    const int quad = lane >> 4;
    const int t0   = blockIdx.x * MT;
    const unsigned xorT = (unsigned)((l15 & 7) << 4);

    const float* cbq = cb + (size_t)Q * KCB * ED;
    const unsigned char* cbbq = cbb + ((size_t)Q << 18);  // Q*16 images
    const float* cnq = cnorm + Q * KCB;

    if (tid < MT) selMin[tid] = ~0ull;
    if (tid == 0) pairCnt = 0;
    __syncthreads();

    // ---- token (B-operand) fragments from global As (linear layout) ----
    bf16x8 bfrag[2][4];
#pragma unroll
    for (int tt = 0; tt < 2; ++tt)
#pragma unroll
        for (int ks = 0; ks < 4; ++ks) {
            int tok = t0 + wid * 32 + tt * 16 + l15;
            bfrag[tt][ks] = *(const bf16x8*)(As + (size_t)tok * 256
                                             + ks * 64 + quad * 16);
        }

    // ---- stage chunk 0 into buf 0: 4 code DMAs + 1 cnorm-trailer DMA ----
    {
        const unsigned char* src = cbbq + (wid << 12) + (lane << 4);
        unsigned char* dst = U + (wid << 12) + (lane << 4);
        GLOAD_LDS16(src,        dst);
        GLOAD_LDS16(src + 1024, dst + 1024);
        GLOAD_LDS16(src + 2048, dst + 2048);
        GLOAD_LDS16(src + 3072, dst + 3072);
        if (lane < 16)
            GLOAD_LDS16((const unsigned char*)cnq + (lane << 4),
                        U + TRL + (lane << 4));
    }

    // ---- chunk loop: double-buffered Bs, counted-vmcnt pipeline ----
    float rmin[2] = {1e30f, 1e30f};   // per-token running min (wave-private)
    for (int cc = 0; cc < NCHUNKS; ++cc) {
        const int cur = cc & 1;

        __builtin_amdgcn_s_barrier();
        __builtin_amdgcn_sched_barrier(0);

        if (cc + 1 < NCHUNKS) {
            const unsigned char* src = cbbq + ((size_t)(cc + 1) << 14)
                                     + (wid << 12) + (lane << 4);
            unsigned char* dst = U + (cur ^ 1) * BUFSZ
                               + (wid << 12) + (lane << 4);
            GLOAD_LDS16(src,        dst);
            GLOAD_LDS16(src + 1024, dst + 1024);
            GLOAD_LDS16(src + 2048, dst + 2048);
            GLOAD_LDS16(src + 3072, dst + 3072);
            if (lane < 16)
                GLOAD_LDS16((const unsigned char*)(cnq + (cc + 1) * NCH)
                                + (lane << 4),
                            U + (cur ^ 1) * BUFSZ + TRL + (lane << 4));
            __builtin_amdgcn_sched_barrier(0);
            asm volatile("s_waitcnt vmcnt(5)" ::: "memory");
        } else {
            __builtin_amdgcn_sched_barrier(0);
            asm volatile("s_waitcnt vmcnt(0)" ::: "memory");
        }
        __builtin_amdgcn_s_barrier();
        __builtin_amdgcn_sched_barrier(0);

        // MFMA: D[code][token] over 64 codes x 32 tokens per wave
        f32x4 acc[4][2];
#pragma unroll
        for (int ct = 0; ct < 4; ++ct)
#pragma unroll
            for (int tt = 0; tt < 2; ++tt)
                acc[ct][tt] = (f32x4){0.f, 0.f, 0.f, 0.f};
        const unsigned char* Ub = U + cur * BUFSZ;
#pragma unroll
        for (int ks = 0; ks < 4; ++ks) {
            bf16x8 afr[4];
#pragma unroll
            for (int ct = 0; ct < 4; ++ct)
                afr[ct] = *(const bf16x8*)(Ub + (ct * 16 + l15) * 256 +
                    (((unsigned)(ks * 64 + quad * 16)) ^ xorT));
#pragma unroll
            for (int ct = 0; ct < 4; ++ct)
#pragma unroll
                for (int tt = 0; tt < 2; ++tt)
                    acc[ct][tt] = __builtin_amdgcn_mfma_f32_16x16x32_bf16(
                        afr[ct], bfrag[tt][ks], acc[ct][tt], 0, 0, 0);
        }

        // scores e = cn - 2*M~ (approx; exact handled by rescore) + min
        const float* cnL = (const float*)(Ub + TRL);
        float tmin[2] = {1e30f, 1e30f};
#pragma unroll
        for (int ct = 0; ct < 4; ++ct) {
            f32x4 cn4 = *(const f32x4*)(cnL + ct * 16 + quad * 4);
#pragma unroll
            for (int tt = 0; tt < 2; ++tt)
#pragma unroll
                for (int r2 = 0; r2 < 4; ++r2) {
                    float m2 = acc[ct][tt][r2];
                    float e = cn4[r2] - (m2 + m2);
                    acc[ct][tt][r2] = e;
                    tmin[tt] = fminf(tmin[tt], e);
                }
        }
#pragma unroll
        for (int tt = 0; tt < 2; ++tt) {
            float v = tmin[tt];
            v = fminf(v, __shfl_xor(v, 16, 64));
            v = fminf(v, __shfl_xor(v, 32, 64));
            rmin[tt] = fminf(rmin[tt], v);
        }

        // candidate pass for THIS chunk (threshold incl. own chunk)
#pragma unroll
        for (int tt = 0; tt < 2; ++tt) {
            int token = wid * 32 + tt * 16 + l15;
            float th = rmin[tt] + MARGIN;
#pragma unroll
            for (int ct = 0; ct < 4; ++ct)
#pragma unroll
                for (int r2 = 0; r2 < 4; ++r2) {
                    float e = acc[ct][tt][r2];
                    if (e <= th) {
                        int code = cc * NCH + ct * 16 + quad * 4 + r2;
                        int pos = atomicAdd(&pairCnt, 1);
                        if (pos < PAIR_CAP)
                            pairList[pos] =
                                ((unsigned)token << 10) | (unsigned)code;
                    }
                }
        }
    }
    __syncthreads();   // all candidate pushes visible

    // ---- exact rescore of candidates (bit-identical to r3 math) ----
    {
        int npair = pairCnt < PAIR_CAP ? pairCnt : PAIR_CAP;
        for (int p = tid; p < npair; p += 256) {
            unsigned pk = pairList[p];
            int t = (pk >> 10) & 127, code = pk & 1023;
            const float* xr = x + (size_t)(t0 + t) * ED;
            const float* cr = cbq + (size_t)code * ED;
            const float* hp[Q > 0 ? Q : 1];
#pragma unroll
            for (int p2 = 0; p2 < Q; ++p2)
                hp[p2] = cb + ((size_t)p2 * KCB
                               + (int)selG[(size_t)(t0 + t) * NQ + p2]) * ED;
            float M = 0.f;
#pragma unroll 4
            for (int k = 0; k < ED; k += 4) {
                float4 v = *(const float4*)(xr + k);
#pragma unroll
                for (int p2 = 0; p2 < Q; ++p2) {
                    float4 c = *(const float4*)(hp[p2] + k);
                    CHAIN4(v, c)
                }
                float4 cv = *(const float4*)(cr + k);
                M = fmaf(v.x, cv.x, M); M = fmaf(v.y, cv.y, M);
                M = fmaf(v.z, cv.z, M); M = fmaf(v.w, cv.w, M);
            }
            float t1 = SsG[t0 + t] - (M + M);       // rounded (contract off)
            float dd = t1 + cnorm[Q * KCB + code];  // rounded
            unsigned long long key =
                ((unsigned long long)fmono(dd) << 10) | (unsigned)code;
            unsigned long long old = selMin[t];
            while (key < old) {
                unsigned long long assumed = old;
                old = atomicCAS(&selMin[t], assumed, key);
                if (old == assumed) break;
            }
        }
    }
    __syncthreads();

    if (tid < MT) {
        int code = (int)(selMin[tid] & 1023ull);
        selG[(size_t)(t0 + tid) * NQ + Q] = (unsigned short)code;
        d_out[(size_t)NT * ED + 1 + (size_t)(t0 + tid) * NQ + Q] = (float)code;
    }
}

// ---------------------------------------------------------------------------
// epilogue_kernel: x_q = x - r4 (exact chain) + loss. One thread per token.
// ---------------------------------------------------------------------------
__global__ void epilogue_kernel(const float* __restrict__ x,
                                const float* __restrict__ cb,
                                const unsigned short* __restrict__ selG,
                                float* __restrict__ d_out) {
#pragma clang fp contract(off)
    __shared__ double lossW[4];
    int tid = threadIdx.x;
    int t = blockIdx.x * 256 + tid;
    const float* xr = x + (size_t)t * ED;
    const float* hp[4];
#pragma unroll
    for (int p2 = 0; p2 < NQ; ++p2)
        hp[p2] = cb + ((size_t)p2 * KCB + (int)selG[t * NQ + p2]) * ED;
    double lo = 0.0;
#pragma unroll 4
    for (int k = 0; k < ED; k += 4) {
        float4 v = *(const float4*)(xr + k);
        float4 o = v;
#pragma unroll
        for (int p2 = 0; p2 < NQ; ++p2) {
            float4 c = *(const float4*)(hp[p2] + k);
            CHAIN4(v, c)
            lo += (double)v.x * v.x + (double)v.y * v.y
                + (double)v.z * v.z + (double)v.w * v.w;
        }
        float4 xq;
        xq.x = o.x - v.x; xq.y = o.y - v.y;
        xq.z = o.z - v.z; xq.w = o.w - v.w;
        *(float4*)(d_out + (size_t)t * ED + k) = xq;
    }
    // loss reduce: wave shuffle -> LDS -> one atomic per block
#pragma unroll
    for (int off = 32; off > 0; off >>= 1) lo += __shfl_down(lo, off, 64);
    if ((tid & 63) == 0) lossW[tid >> 6] = lo;
    __syncthreads();
    if (tid == 0) {
        double s = lossW[0] + lossW[1] + lossW[2] + lossW[3];
        atomicAdd(d_out + (size_t)NT * ED,
                  (float)(s * (0.25 / (4.0 * (double)NT * ED))));
    }
}

// ===========================================================================
// FALLBACK MONOLITH (r5-validated, used when workspace is small)
// ===========================================================================
template<int Q>
__device__ __forceinline__ void run_stage_mono(
    const float* __restrict__ x, const float* __restrict__ cb,
    const float* __restrict__ cnorm, const unsigned char* __restrict__ cbb,
    float* __restrict__ d_out,
    unsigned char* U, unsigned long long* selMin, float* Ss,
    unsigned short* selSh, unsigned* pairList, int* pairCnt,
    int tid, int lane, int wid, int l15, int quad, int t0, unsigned xorT) {
#pragma clang fp contract(off)
    const float* cbq = cb + (size_t)Q * KCB * ED;
    const unsigned char* cbbq = cbb + ((size_t)Q << 18);
    const float* cnq = cnorm + Q * KCB;

    if (tid < MT) selMin[tid] = ~0ull;
    if (tid == 0) *pairCnt = 0;
    __syncthreads();

    if (tid < MT) {
        int t = tid;
        const float* xr = x + (size_t)(t0 + t) * ED;
        const float* hp[Q > 0 ? Q : 1];
#pragma unroll
        for (int p2 = 0; p2 < Q; ++p2)
            hp[p2] = cb + ((size_t)p2 * KCB + (int)selSh[t * NQ + p2]) * ED;
        unsigned char* Aw = U + t * 256;
        unsigned xw = (unsigned)((t & 7) << 4);
        float r8[8];
#pragma unroll
        for (int m = 0; m < 8; ++m) r8[m] = 0.f;
#pragma unroll 4
        for (int i = 0; i < 32; ++i) {
            float4 v = *(const float4*)(xr + (i << 2));
#pragma unroll
            for (int p2 = 0; p2 < Q; ++p2) {
                float4 c = *(const float4*)(hp[p2] + (i << 2));
                CHAIN4(v, c)
            }
            uint2 w2;
            w2.x = packbf(v.x, v.y); w2.y = packbf(v.z, v.w);
            *(uint2*)(Aw + (((((unsigned)(i >> 1)) << 4) ^ xw)
                            | ((unsigned)(i & 1) << 3))) = w2;
            int base = (i & 1) << 2;
            float px = v.x * v.x, py = v.y * v.y,
                  pz = v.z * v.z, pw = v.w * v.w;
            r8[base + 0] = r8[base + 0] + px;
            r8[base + 1] = r8[base + 1] + py;
            r8[base + 2] = r8[base + 2] + pz;
            r8[base + 3] = r8[base + 3] + pw;
        }
        Ss[t] = ((r8[0] + r8[1]) + (r8[2] + r8[3]))
              + ((r8[4] + r8[5]) + (r8[6] + r8[7]));
    }
    __syncthreads();

    bf16x8 bfrag[2][4];
#pragma unroll
    for (int tt = 0; tt < 2; ++tt)
#pragma unroll
        for (int ks = 0; ks < 4; ++ks) {
            int tok = wid * 32 + tt * 16 + l15;
            bfrag[tt][ks] = *(const bf16x8*)(U + tok * 256 +
                (((unsigned)(ks * 64 + quad * 16)) ^ xorT));
        }
    __syncthreads();

    {
        const unsigned char* src = cbbq + (wid << 12) + (lane << 4);
        unsigned char* dst = U + (wid << 12) + (lane << 4);
        GLOAD_LDS16(src,        dst);
        GLOAD_LDS16(src + 1024, dst + 1024);
        GLOAD_LDS16(src + 2048, dst + 2048);
        GLOAD_LDS16(src + 3072, dst + 3072);
        if (lane < 16)
            GLOAD_LDS16((const unsigned char*)cnq + (lane << 4),
                        U + TRL + (lane << 4));
    }

    float rmin[2] = {1e30f, 1e30f};
    for (int cc = 0; cc < NCHUNKS; ++cc) {
        const int cur = cc & 1;
        __builtin_amdgcn_s_barrier();
        __builtin_amdgcn_sched_barrier(0);
        if (cc + 1 < NCHUNKS) {
            const unsigned char* src = cbbq + ((size_t)(cc + 1) << 14)
                                     + (wid << 12) + (lane << 4);
            unsigned char* dst = U + (cur ^ 1) * BUFSZ
                               + (wid << 12) + (lane << 4);
            GLOAD_LDS16(src,        dst);
            GLOAD_LDS16(src + 1024, dst + 1024);
            GLOAD_LDS16(src + 2048, dst + 2048);
            GLOAD_LDS16(src + 3072, dst + 3072);
            if (lane < 16)
                GLOAD_LDS16((const unsigned char*)(cnq + (cc + 1) * NCH)
                                + (lane << 4),
                            U + (cur ^ 1) * BUFSZ + TRL + (lane << 4));
            __builtin_amdgcn_sched_barrier(0);
            asm volatile("s_waitcnt vmcnt(5)" ::: "memory");
        } else {
            __builtin_amdgcn_sched_barrier(0);
            asm volatile("s_waitcnt vmcnt(0)" ::: "memory");
        }
        __builtin_amdgcn_s_barrier();
        __builtin_amdgcn_sched_barrier(0);

        f32x4 acc[4][2];
#pragma unroll
        for (int ct = 0; ct < 4; ++ct)
#pragma unroll
            for (int tt = 0; tt < 2; ++tt)
                acc[ct][tt] = (f32x4){0.f, 0.f, 0.f, 0.f};
        const unsigned char* Ub = U + cur * BUFSZ;
#pragma unroll
        for (int ks = 0; ks < 4; ++ks) {
            bf16x8 afr[4];
#pragma unroll
            for (int ct = 0; ct < 4; ++ct)
                afr[ct] = *(const bf16x8*)(Ub + (ct * 16 + l15) * 256 +
                    (((unsigned)(ks * 64 + quad * 16)) ^ xorT));
#pragma unroll
            for (int ct = 0; ct < 4; ++ct)
#pragma unroll
                for (int tt = 0; tt < 2; ++tt)
                    acc[ct][tt] = __builtin_amdgcn_mfma_f32_16x16x32_bf16(
                        afr[ct], bfrag[tt][ks], acc[ct][tt], 0, 0, 0);
        }

        const float* cnL = (const float*)(Ub + TRL);
        float tmin[2] = {1e30f, 1e30f};
#pragma unroll
        for (int ct = 0; ct < 4; ++ct) {
            f32x4 cn4 = *(const f32x4*)(cnL + ct * 16 + quad * 4);
#pragma unroll
            for (int tt = 0; tt < 2; ++tt)
#pragma unroll
                for (int r2 = 0; r2 < 4; ++r2) {
                    float m2 = acc[ct][tt][r2];
                    float e = cn4[r2] - (m2 + m2);
                    acc[ct][tt][r2] = e;
                    tmin[tt] = fminf(tmin[tt], e);
                }
        }
#pragma unroll
        for (int tt = 0; tt < 2; ++tt) {
            float v = tmin[tt];
            v = fminf(v, __shfl_xor(v, 16, 64));
            v = fminf(v, __shfl_xor(v, 32, 64));
            rmin[tt] = fminf(rmin[tt], v);
        }
#pragma unroll
        for (int tt = 0; tt < 2; ++tt) {
            int token = wid * 32 + tt * 16 + l15;
            float th = rmin[tt] + MARGIN;
#pragma unroll
            for (int ct = 0; ct < 4; ++ct)
#pragma unroll
                for (int r2 = 0; r2 < 4; ++r2) {
                    float e = acc[ct][tt][r2];
                    if (e <= th) {
                        int code = cc * NCH + ct * 16 + quad * 4 + r2;
                        int pos = atomicAdd(pairCnt, 1);
                        if (pos < PAIR_CAP)
                            pairList[pos] =
                                ((unsigned)token << 10) | (unsigned)code;
                    }
                }
        }
    }
    __syncthreads();

    {
        int npair = *pairCnt < PAIR_CAP ? *pairCnt : PAIR_CAP;
        for (int p = tid; p < npair; p += 256) {
            unsigned pk = pairList[p];
            int t = (pk >> 10) & 127, code = pk & 1023;
            const float* xr = x + (size_t)(t0 + t) * ED;
            const float* cr = cbq + (size_t)code * ED;
            const float* hp[Q > 0 ? Q : 1];
#pragma unroll
            for (int p2 = 0; p2 < Q; ++p2)
                hp[p2] = cb + ((size_t)p2 * KCB + (int)selSh[t * NQ + p2]) * ED;
            float M = 0.f;
#pragma unroll 4
            for (int k = 0; k < ED; k += 4) {
                float4 v = *(const float4*)(xr + k);
#pragma unroll
                for (int p2 = 0; p2 < Q; ++p2) {
                    float4 c = *(const float4*)(hp[p2] + k);
                    CHAIN4(v, c)
                }
                float4 cv = *(const float4*)(cr + k);
                M = fmaf(v.x, cv.x, M); M = fmaf(v.y, cv.y, M);
                M = fmaf(v.z, cv.z, M); M = fmaf(v.w, cv.w, M);
            }
            float t1 = Ss[t] - (M + M);
            float dd = t1 + cnorm[Q * KCB + code];
            unsigned long long key =
                ((unsigned long long)fmono(dd) << 10) | (unsigned)code;
            unsigned long long old = selMin[t];
            while (key < old) {
                unsigned long long assumed = old;
                old = atomicCAS(&selMin[t], assumed, key);
                if (old == assumed) break;
            }
        }
    }
    __syncthreads();

    if (tid < MT) {
        int code = (int)(selMin[tid] & 1023ull);
        selSh[tid * NQ + Q] = (unsigned short)code;
        d_out[(size_t)NT * ED + 1 + (size_t)(t0 + tid) * NQ + Q] = (float)code;
    }
    __syncthreads();
}

__global__ __launch_bounds__(256, 3) void rvq_mono(const float* __restrict__ x,
                                                   const float* __restrict__ cb,
                                                   const float* __restrict__ cnorm,
                                                   const unsigned char* __restrict__ cbb,
                                                   float* __restrict__ d_out) {
#pragma clang fp contract(off)
    __shared__ __align__(16) unsigned char U[2 * BUFSZ];
    __shared__ unsigned long long selMin[MT];
    __shared__ float    Ss[MT];
    __shared__ unsigned short selSh[MT * NQ];
    __shared__ unsigned pairList[PAIR_CAP];
    __shared__ int      pairCnt;
    __shared__ double   lossW[4];

    const int tid  = threadIdx.x;
    const int lane = tid & 63;
    const int wid  = tid >> 6;
    const int l15  = lane & 15;
    const int quad = lane >> 4;
    const int t0   = blockIdx.x * MT;
    const unsigned xorT = (unsigned)((l15 & 7) << 4);

    run_stage_mono<0>(x, cb, cnorm, cbb, d_out, U, selMin, Ss, selSh,
                      pairList, &pairCnt, tid, lane, wid, l15, quad, t0, xorT);
    run_stage_mono<1>(x, cb, cnorm, cbb, d_out, U, selMin, Ss, selSh,
                      pairList, &pairCnt, tid, lane, wid, l15, quad, t0, xorT);
    run_stage_mono<2>(x, cb, cnorm, cbb, d_out, U, selMin, Ss, selSh,
                      pairList, &pairCnt, tid, lane, wid, l15, quad, t0, xorT);
    run_stage_mono<3>(x, cb, cnorm, cbb, d_out, U, selMin, Ss, selSh,
                      pairList, &pairCnt, tid, lane, wid, l15, quad, t0, xorT);

    double lossTot = 0.0;
    if (tid < MT) {
        int t = tid;
        const float* xr = x + (size_t)(t0 + t) * ED;
        const float* hp[4];
#pragma unroll
        for (int p2 = 0; p2 < NQ; ++p2)
            hp[p2] = cb + ((size_t)p2 * KCB + (int)selSh[t * NQ + p2]) * ED;
        double lo = 0.0;
#pragma unroll 4
        for (int k = 0; k < ED; k += 4) {
            float4 v = *(const float4*)(xr + k);
            float4 o = v;
#pragma unroll
            for (int p2 = 0; p2 < NQ; ++p2) {
                float4 c = *(const float4*)(hp[p2] + k);
                CHAIN4(v, c)
                lo += (double)v.x * v.x + (double)v.y * v.y
                    + (double)v.z * v.z + (double)v.w * v.w;
            }
            float4 xq;
            xq.x = o.x - v.x; xq.y = o.y - v.y;
            xq.z = o.z - v.z; xq.w = o.w - v.w;
            *(float4*)(d_out + (size_t)(t0 + t) * ED + k) = xq;
        }
        lossTot = lo;
    }
    double l = lossTot;
#pragma unroll
    for (int off = 32; off > 0; off >>= 1) l += __shfl_down(l, off, 64);
    if ((tid & 63) == 0) lossW[tid >> 6] = l;
    __syncthreads();
    if (tid == 0) {
        double s = lossW[0] + lossW[1] + lossW[2] + lossW[3];
        atomicAdd(d_out + (size_t)NT * ED,
                  (float)(s * (0.25 / (4.0 * (double)NT * ED))));
    }
}

// ---------------------------------------------------------------------------
// workspace: [0,16K) cnorm | [16K,16K+1M) cbb | then selG 1M | Ss 512K |
// As 32M (split path only; host checks ws_size and falls back to monolith).
// ---------------------------------------------------------------------------
extern "C" void kernel_launch(void* const* d_in, const int* in_sizes, int n_in,
                              void* d_out, int out_size, void* d_ws, size_t ws_size,
                              hipStream_t stream) {
    const float* x  = (const float*)d_in[0];
    const float* cb = (const float*)d_in[1];
    float* out   = (float*)d_out;
    unsigned char* ws = (unsigned char*)d_ws;

    float* cnorm = (float*)ws;                                 // 16 KB
    unsigned char* cbb = ws + 16384;                           // 1 MiB
    unsigned short* selG = (unsigned short*)(ws + 16384 + (1u << 20));  // 1 MiB
    float* SsG = (float*)(ws + 16384 + (2u << 20));            // 512 KiB
    unsigned char* As = ws + 16384 + (2u << 20) + (1u << 19);  // 32 MiB
    const size_t need = 16384 + (2ull << 20) + (1ull << 19) + (32ull << 20);

    prep_kernel<<<16, 256, 0, stream>>>(cb, cnorm, out + (size_t)NT * ED);
    cvt_kernel<<<256, 256, 0, stream>>>(cb, cbb);

    if (ws_size >= need) {
        s_kernel<0><<<NT / 256, 256, 0, stream>>>(x, cb, selG, As, SsG);
        select_kernel<0><<<NBLK, 256, 0, stream>>>(x, cb, cnorm, cbb, As, SsG, selG, out);
        s_kernel<1><<<NT / 256, 256, 0, stream>>>(x, cb, selG, As, SsG);
        select_kernel<1><<<NBLK, 256, 0, stream>>>(x, cb, cnorm, cbb, As, SsG, selG, out);
        s_kernel<2><<<NT / 256, 256, 0, stream>>>(x, cb, selG, As, SsG);
        select_kernel<2><<<NBLK, 256, 0, stream>>>(x, cb, cnorm, cbb, As, SsG, selG, out);
        s_kernel<3><<<NT / 256, 256, 0, stream>>>(x, cb, selG, As, SsG);
        select_kernel<3><<<NBLK, 256, 0, stream>>>(x, cb, cnorm, cbb, As, SsG, selG, out);
        epilogue_kernel<<<NT / 256, 256, 0, stream>>>(x, cb, selG, out);
    } else {
        rvq_mono<<<NBLK, 256, 0, stream>>>(x, cb, cnorm, cbb, out);
    }
}

// Round 8
// 890.468 us; speedup vs baseline: 1.4127x; 1.3244x over previous
//
#include <hip/hip_runtime.h>

#define NT 131072
#define ED 128
#define KCB 1024
#define NQ 4

#define MT 128                 // tokens per select-block
#define NBLK (NT / MT)         // 1024 blocks
#define NCH 64                 // codes per chunk
#define NCHUNKS (KCB / NCH)    // 16
#define PAIR_CAP 1024
#define MARGIN 1.5e-3f

#define TRL 16384              // trailer (cnorm slice) offset inside a Bs buf
#define BUFSZ 16640            // 16 KB codes + 256 B cnorm trailer

typedef __attribute__((ext_vector_type(8))) short bf16x8;
typedef __attribute__((ext_vector_type(4))) float f32x4;

#define ASG __attribute__((address_space(1)))
#define ASL __attribute__((address_space(3)))
#define GLOAD_LDS16(g, l) \
    __builtin_amdgcn_global_load_lds((const ASG void*)(g), (ASL void*)(l), 16, 0, 0)

// ---- bf16 round-to-nearest-even, returns low 16 bits ----
__device__ __forceinline__ unsigned bf16rne(float f) {
    unsigned u = __float_as_uint(f);
    u += 0x7fffu + ((u >> 16) & 1u);
    return u >> 16;
}
__device__ __forceinline__ unsigned packbf(float a, float b) {
    return bf16rne(a) | (bf16rne(b) << 16);
}
// ---- monotone float->uint (unsigned compare preserves float order) ----
__device__ __forceinline__ unsigned fmono(float f) {
    unsigned u = __float_as_uint(f);
    return (u & 0x80000000u) ? ~u : (u | 0x80000000u);
}

// ---------------------------------------------------------------------------
// prep: cnorm[c] = np.sum(cb*cb, axis=1) fp32 numpy-pairwise (validated r3);
// zero the loss slot.
// ---------------------------------------------------------------------------
__global__ void prep_kernel(const float* __restrict__ cb,
                            float* __restrict__ cnorm,
                            float* __restrict__ loss_slot) {
#pragma clang fp contract(off)
    int c = blockIdx.x * 256 + threadIdx.x;   // 0..4095
    if (blockIdx.x == 0 && threadIdx.x == 0) loss_slot[0] = 0.0f;
    const float* row = cb + (size_t)c * ED;
    float r8[8];
#pragma unroll
    for (int m = 0; m < 8; ++m) { float v = row[m]; r8[m] = v * v; }
    for (int i = 8; i < ED; i += 8) {
#pragma unroll
        for (int m = 0; m < 8; ++m) {
            float v = row[i + m];
            float p = v * v;
            r8[m] = r8[m] + p;
        }
    }
    cnorm[c] = ((r8[0] + r8[1]) + (r8[2] + r8[3]))
             + ((r8[4] + r8[5]) + (r8[6] + r8[7]));
}

// ---------------------------------------------------------------------------
// cvt: codebooks -> bf16 swizzled chunk-linear image (r5-validated layout)
// for pure global_load_lds staging in the select kernel.
// ---------------------------------------------------------------------------
__global__ void cvt_kernel(const float* __restrict__ cb,
                           unsigned char* __restrict__ cbb) {
#pragma clang fp contract(off)
    int id = blockIdx.x * 256 + threadIdx.x;        // 0..65535
    int rg = id >> 4;                               // global code row 0..4095
    int j  = id & 15;                               // 16B block within row
    const float* src = cb + (size_t)rg * ED + j * 8;
    float4 a = *(const float4*)(src);
    float4 b = *(const float4*)(src + 4);
    uint4 w;
    w.x = packbf(a.x, a.y); w.y = packbf(a.z, a.w);
    w.z = packbf(b.x, b.y); w.w = packbf(b.z, b.w);
    size_t dst = ((size_t)(rg >> 6) << 14)          // 16 KiB chunk image
               + (size_t)((rg & 63) << 8)           // row * 256 B
               + (size_t)((j ^ (rg & 7)) << 4);     // swizzled 16B slot
    *(uint4*)(cbb + dst) = w;
}

// ---------------------------------------------------------------------------
// per-element straight-through chain step (validated r3)
#define CHAIN4(V, C)                                                     \
    { float d1x = (C).x - (V).x, d1y = (C).y - (V).y,                    \
            d1z = (C).z - (V).z, d1w = (C).w - (V).w;                    \
      float qtx = (V).x + d1x, qty = (V).y + d1y,                        \
            qtz = (V).z + d1z, qtw = (V).w + d1w;                        \
      (V).x = (V).x - qtx; (V).y = (V).y - qty;                          \
      (V).z = (V).z - qtz; (V).w = (V).w - qtw; }

// ===========================================================================
// SPLIT PATH. MODE=1: residual-cache (rG fp32). MODE=0: r7 As path.
// ===========================================================================

// ---------------------------------------------------------------------------
// s_kernel<Q,MODE>: token-parallel residual/S phase. One thread per token.
// MODE=1 writes fp32 residual rG; MODE=0 writes bf16 As (linear). Math
// byte-identical to the validated monolith S-phase.
// ---------------------------------------------------------------------------
template<int Q, int MODE>
__global__ void s_kernel(const float* __restrict__ x,
                         const float* __restrict__ cb,
                         const unsigned short* __restrict__ selG,
                         unsigned char* __restrict__ As,
                         float* __restrict__ rG,
                         float* __restrict__ SsG) {
#pragma clang fp contract(off)
    int t = blockIdx.x * 256 + threadIdx.x;   // 0..NT-1
    const float* xr = x + (size_t)t * ED;
    const float* hp[Q > 0 ? Q : 1];
#pragma unroll
    for (int p2 = 0; p2 < Q; ++p2)
        hp[p2] = cb + ((size_t)p2 * KCB + (int)selG[t * NQ + p2]) * ED;
    unsigned char* Aw = As + (size_t)t * 256;
    float* rW = rG + (size_t)t * ED;
    float r8[8];
#pragma unroll
    for (int m = 0; m < 8; ++m) r8[m] = 0.f;
    unsigned w0 = 0, w1 = 0;
#pragma unroll 4
    for (int i = 0; i < 32; ++i) {
        float4 v = *(const float4*)(xr + (i << 2));
#pragma unroll
        for (int p2 = 0; p2 < Q; ++p2) {
            float4 c = *(const float4*)(hp[p2] + (i << 2));
            CHAIN4(v, c)
        }
        if (MODE == 1) {
            *(float4*)(rW + (i << 2)) = v;     // exact fp32 residual
        } else {
            if ((i & 1) == 0) {
                w0 = packbf(v.x, v.y); w1 = packbf(v.z, v.w);
            } else {
                uint4 w;
                w.x = w0; w.y = w1;
                w.z = packbf(v.x, v.y); w.w = packbf(v.z, v.w);
                *(uint4*)(Aw + ((i >> 1) << 4)) = w;
            }
        }
        // numpy 8-acc squares: k=4i+j -> m=(4i+j)&7
        int base = (i & 1) << 2;
        float px = v.x * v.x, py = v.y * v.y,
              pz = v.z * v.z, pw = v.w * v.w;
        r8[base + 0] = r8[base + 0] + px;
        r8[base + 1] = r8[base + 1] + py;
        r8[base + 2] = r8[base + 2] + pz;
        r8[base + 3] = r8[base + 3] + pw;
    }
    SsG[t] = ((r8[0] + r8[1]) + (r8[2] + r8[3]))
           + ((r8[4] + r8[5]) + (r8[6] + r8[7]));
}

// ---------------------------------------------------------------------------
// select_kernel<Q,MODE>: GEMM-screen (r5-validated chunk loop) + rescore.
// MODE=1: bfrag packed in-reg from rG (bit-identical bf16); rescore reads
// rG + code row only (M chain fmaf-order-identical). MODE=0: r7 verbatim.
// ---------------------------------------------------------------------------
template<int Q, int MODE>
__global__ __launch_bounds__(256, 3) void select_kernel(
    const float* __restrict__ x, const float* __restrict__ cb,
    const float* __restrict__ cnorm, const unsigned char* __restrict__ cbb,
    const unsigned char* __restrict__ As, const float* __restrict__ rG,
    const float* __restrict__ SsG,
    unsigned short* __restrict__ selG, float* __restrict__ d_out) {
#pragma clang fp contract(off)
    __shared__ __align__(16) unsigned char U[2 * BUFSZ];   // Bs dbuf + trailers
    __shared__ unsigned long long selMin[MT];
    __shared__ unsigned pairList[PAIR_CAP];
    __shared__ int      pairCnt;

    const int tid  = threadIdx.x;
    const int lane = tid & 63;
    const int wid  = tid >> 6;     // wave 0..3 -> tokens [wid*32, wid*32+32)
    const int l15  = lane & 15;
    const int quad = lane >> 4;
    const int t0   = blockIdx.x * MT;
    const unsigned xorT = (unsigned)((l15 & 7) << 4);

    const float* cbq = cb + (size_t)Q * KCB * ED;
    const unsigned char* cbbq = cbb + ((size_t)Q << 18);  // Q*16 images
    const float* cnq = cnorm + Q * KCB;

    if (tid < MT) selMin[tid] = ~0ull;
    if (tid == 0) pairCnt = 0;
    __syncthreads();

    // ---- token (B-operand) fragments ----
    bf16x8 bfrag[2][4];
#pragma unroll
    for (int tt = 0; tt < 2; ++tt)
#pragma unroll
        for (int ks = 0; ks < 4; ++ks) {
            int tok = t0 + wid * 32 + tt * 16 + l15;
            if (MODE == 1) {
                const float* rr = rG + (size_t)tok * ED + ks * 32 + quad * 8;
                float4 a = *(const float4*)(rr);
                float4 b = *(const float4*)(rr + 4);
                uint4 w;
                w.x = packbf(a.x, a.y); w.y = packbf(a.z, a.w);
                w.z = packbf(b.x, b.y); w.w = packbf(b.z, b.w);
                bfrag[tt][ks] = __builtin_bit_cast(bf16x8, w);
            } else {
                bfrag[tt][ks] = *(const bf16x8*)(As + (size_t)tok * 256
                                                 + ks * 64 + quad * 16);
            }
        }

    // ---- stage chunk 0 into buf 0: 4 code DMAs + 1 cnorm-trailer DMA ----
    {
        const unsigned char* src = cbbq + (wid << 12) + (lane << 4);
        unsigned char* dst = U + (wid << 12) + (lane << 4);
        GLOAD_LDS16(src,        dst);
        GLOAD_LDS16(src + 1024, dst + 1024);
        GLOAD_LDS16(src + 2048, dst + 2048);
        GLOAD_LDS16(src + 3072, dst + 3072);
        if (lane < 16)
            GLOAD_LDS16((const unsigned char*)cnq + (lane << 4),
                        U + TRL + (lane << 4));
    }

    // ---- chunk loop: double-buffered Bs, counted-vmcnt pipeline ----
    float rmin[2] = {1e30f, 1e30f};   // per-token running min (wave-private)
    for (int cc = 0; cc < NCHUNKS; ++cc) {
        const int cur = cc & 1;

        __builtin_amdgcn_s_barrier();
        __builtin_amdgcn_sched_barrier(0);

        if (cc + 1 < NCHUNKS) {
            const unsigned char* src = cbbq + ((size_t)(cc + 1) << 14)
                                     + (wid << 12) + (lane << 4);
            unsigned char* dst = U + (cur ^ 1) * BUFSZ
                               + (wid << 12) + (lane << 4);
            GLOAD_LDS16(src,        dst);
            GLOAD_LDS16(src + 1024, dst + 1024);
            GLOAD_LDS16(src + 2048, dst + 2048);
            GLOAD_LDS16(src + 3072, dst + 3072);
            if (lane < 16)
                GLOAD_LDS16((const unsigned char*)(cnq + (cc + 1) * NCH)
                                + (lane << 4),
                            U + (cur ^ 1) * BUFSZ + TRL + (lane << 4));
            __builtin_amdgcn_sched_barrier(0);
            asm volatile("s_waitcnt vmcnt(5)" ::: "memory");
        } else {
            __builtin_amdgcn_sched_barrier(0);
            asm volatile("s_waitcnt vmcnt(0)" ::: "memory");
        }
        __builtin_amdgcn_s_barrier();
        __builtin_amdgcn_sched_barrier(0);

        // MFMA: D[code][token] over 64 codes x 32 tokens per wave
        f32x4 acc[4][2];
#pragma unroll
        for (int ct = 0; ct < 4; ++ct)
#pragma unroll
            for (int tt = 0; tt < 2; ++tt)
                acc[ct][tt] = (f32x4){0.f, 0.f, 0.f, 0.f};
        const unsigned char* Ub = U + cur * BUFSZ;
#pragma unroll
        for (int ks = 0; ks < 4; ++ks) {
            bf16x8 afr[4];
#pragma unroll
            for (int ct = 0; ct < 4; ++ct)
                afr[ct] = *(const bf16x8*)(Ub + (ct * 16 + l15) * 256 +
                    (((unsigned)(ks * 64 + quad * 16)) ^ xorT));
#pragma unroll
            for (int ct = 0; ct < 4; ++ct)
#pragma unroll
                for (int tt = 0; tt < 2; ++tt)
                    acc[ct][tt] = __builtin_amdgcn_mfma_f32_16x16x32_bf16(
                        afr[ct], bfrag[tt][ks], acc[ct][tt], 0, 0, 0);
        }

        // scores e = cn - 2*M~ (approx; exact handled by rescore) + min
        const float* cnL = (const float*)(Ub + TRL);
        float tmin[2] = {1e30f, 1e30f};
#pragma unroll
        for (int ct = 0; ct < 4; ++ct) {
            f32x4 cn4 = *(const f32x4*)(cnL + ct * 16 + quad * 4);
#pragma unroll
            for (int tt = 0; tt < 2; ++tt)
#pragma unroll
                for (int r2 = 0; r2 < 4; ++r2) {
                    float m2 = acc[ct][tt][r2];
                    float e = cn4[r2] - (m2 + m2);
                    acc[ct][tt][r2] = e;
                    tmin[tt] = fminf(tmin[tt], e);
                }
        }
#pragma unroll
        for (int tt = 0; tt < 2; ++tt) {
            float v = tmin[tt];
            v = fminf(v, __shfl_xor(v, 16, 64));
            v = fminf(v, __shfl_xor(v, 32, 64));
            rmin[tt] = fminf(rmin[tt], v);
        }

        // candidate pass for THIS chunk (threshold incl. own chunk)
#pragma unroll
        for (int tt = 0; tt < 2; ++tt) {
            int token = wid * 32 + tt * 16 + l15;
            float th = rmin[tt] + MARGIN;
#pragma unroll
            for (int ct = 0; ct < 4; ++ct)
#pragma unroll
                for (int r2 = 0; r2 < 4; ++r2) {
                    float e = acc[ct][tt][r2];
                    if (e <= th) {
                        int code = cc * NCH + ct * 16 + quad * 4 + r2;
                        int pos = atomicAdd(&pairCnt, 1);
                        if (pos < PAIR_CAP)
                            pairList[pos] =
                                ((unsigned)token << 10) | (unsigned)code;
                    }
                }
        }
    }
    __syncthreads();   // all candidate pushes visible

    // ---- exact rescore of candidates ----
    {
        int npair = pairCnt < PAIR_CAP ? pairCnt : PAIR_CAP;
        for (int p = tid; p < npair; p += 256) {
            unsigned pk = pairList[p];
            int t = (pk >> 10) & 127, code = pk & 1023;
            const float* cr = cbq + (size_t)code * ED;
            float M = 0.f;
            if (MODE == 1) {
                // residual cached in rG: M chain fmaf-order-identical
                const float* rr = rG + (size_t)(t0 + t) * ED;
#pragma unroll 4
                for (int k = 0; k < ED; k += 4) {
                    float4 v = *(const float4*)(rr + k);
                    float4 cv = *(const float4*)(cr + k);
                    M = fmaf(v.x, cv.x, M); M = fmaf(v.y, cv.y, M);
                    M = fmaf(v.z, cv.z, M); M = fmaf(v.w, cv.w, M);
                }
            } else {
                const float* xr = x + (size_t)(t0 + t) * ED;
                const float* hp[Q > 0 ? Q : 1];
#pragma unroll
                for (int p2 = 0; p2 < Q; ++p2)
                    hp[p2] = cb + ((size_t)p2 * KCB
                               + (int)selG[(size_t)(t0 + t) * NQ + p2]) * ED;
#pragma unroll 4
                for (int k = 0; k < ED; k += 4) {
                    float4 v = *(const float4*)(xr + k);
#pragma unroll
                    for (int p2 = 0; p2 < Q; ++p2) {
                        float4 c = *(const float4*)(hp[p2] + k);
                        CHAIN4(v, c)
                    }
                    float4 cv = *(const float4*)(cr + k);
                    M = fmaf(v.x, cv.x, M); M = fmaf(v.y, cv.y, M);
                    M = fmaf(v.z, cv.z, M); M = fmaf(v.w, cv.w, M);
                }
            }
            float t1 = SsG[t0 + t] - (M + M);       // rounded (contract off)
            float dd = t1 + cnorm[Q * KCB + code];  // rounded
            unsigned long long key =
                ((unsigned long long)fmono(dd) << 10) | (unsigned)code;
            unsigned long long old = selMin[t];
            while (key < old) {
                unsigned long long assumed = old;
                old = atomicCAS(&selMin[t], assumed, key);
                if (old == assumed) break;
            }
        }
    }
    __syncthreads();

    if (tid < MT) {
        int code = (int)(selMin[tid] & 1023ull);
        selG[(size_t)(t0 + tid) * NQ + Q] = (unsigned short)code;
        d_out[(size_t)NT * ED + 1 + (size_t)(t0 + tid) * NQ + Q] = (float)code;
    }
}

// ---------------------------------------------------------------------------
// epilogue_kernel: x_q = x - r4 (exact chain) + loss. One thread per token.
// ---------------------------------------------------------------------------
__global__ void epilogue_kernel(const float* __restrict__ x,
                                const float* __restrict__ cb,
                                const unsigned short* __restrict__ selG,
                                float* __restrict__ d_out) {
#pragma clang fp contract(off)
    __shared__ double lossW[4];
    int tid = threadIdx.x;
    int t = blockIdx.x * 256 + tid;
    const float* xr = x + (size_t)t * ED;
    const float* hp[4];
#pragma unroll
    for (int p2 = 0; p2 < NQ; ++p2)
        hp[p2] = cb + ((size_t)p2 * KCB + (int)selG[t * NQ + p2]) * ED;
    double lo = 0.0;
#pragma unroll 4
    for (int k = 0; k < ED; k += 4) {
        float4 v = *(const float4*)(xr + k);
        float4 o = v;
#pragma unroll
        for (int p2 = 0; p2 < NQ; ++p2) {
            float4 c = *(const float4*)(hp[p2] + k);
            CHAIN4(v, c)
            lo += (double)v.x * v.x + (double)v.y * v.y
                + (double)v.z * v.z + (double)v.w * v.w;
        }
        float4 xq;
        xq.x = o.x - v.x; xq.y = o.y - v.y;
        xq.z = o.z - v.z; xq.w = o.w - v.w;
        *(float4*)(d_out + (size_t)t * ED + k) = xq;
    }
#pragma unroll
    for (int off = 32; off > 0; off >>= 1) lo += __shfl_down(lo, off, 64);
    if ((tid & 63) == 0) lossW[tid >> 6] = lo;
    __syncthreads();
    if (tid == 0) {
        double s = lossW[0] + lossW[1] + lossW[2] + lossW[3];
        atomicAdd(d_out + (size_t)NT * ED,
                  (float)(s * (0.25 / (4.0 * (double)NT * ED))));
    }
}

// ===========================================================================
// FALLBACK MONOLITH (r5-validated, used when workspace is tiny)
// ===========================================================================
template<int Q>
__device__ __forceinline__ void run_stage_mono(
    const float* __restrict__ x, const float* __restrict__ cb,
    const float* __restrict__ cnorm, const unsigned char* __restrict__ cbb,
    float* __restrict__ d_out,
    unsigned char* U, unsigned long long* selMin, float* Ss,
    unsigned short* selSh, unsigned* pairList, int* pairCnt,
    int tid, int lane, int wid, int l15, int quad, int t0, unsigned xorT) {
#pragma clang fp contract(off)
    const float* cbq = cb + (size_t)Q * KCB * ED;
    const unsigned char* cbbq = cbb + ((size_t)Q << 18);
    const float* cnq = cnorm + Q * KCB;

    if (tid < MT) selMin[tid] = ~0ull;
    if (tid == 0) *pairCnt = 0;
    __syncthreads();

    if (tid < MT) {
        int t = tid;
        const float* xr = x + (size_t)(t0 + t) * ED;
        const float* hp[Q > 0 ? Q : 1];
#pragma unroll
        for (int p2 = 0; p2 < Q; ++p2)
            hp[p2] = cb + ((size_t)p2 * KCB + (int)selSh[t * NQ + p2]) * ED;
        unsigned char* Aw = U + t * 256;
        unsigned xw = (unsigned)((t & 7) << 4);
        float r8[8];
#pragma unroll
        for (int m = 0; m < 8; ++m) r8[m] = 0.f;
#pragma unroll 4
        for (int i = 0; i < 32; ++i) {
            float4 v = *(const float4*)(xr + (i << 2));
#pragma unroll
            for (int p2 = 0; p2 < Q; ++p2) {
                float4 c = *(const float4*)(hp[p2] + (i << 2));
                CHAIN4(v, c)
            }
            uint2 w2;
            w2.x = packbf(v.x, v.y); w2.y = packbf(v.z, v.w);
            *(uint2*)(Aw + (((((unsigned)(i >> 1)) << 4) ^ xw)
                            | ((unsigned)(i & 1) << 3))) = w2;
            int base = (i & 1) << 2;
            float px = v.x * v.x, py = v.y * v.y,
                  pz = v.z * v.z, pw = v.w * v.w;
            r8[base + 0] = r8[base + 0] + px;
            r8[base + 1] = r8[base + 1] + py;
            r8[base + 2] = r8[base + 2] + pz;
            r8[base + 3] = r8[base + 3] + pw;
        }
        Ss[t] = ((r8[0] + r8[1]) + (r8[2] + r8[3]))
              + ((r8[4] + r8[5]) + (r8[6] + r8[7]));
    }
    __syncthreads();

    bf16x8 bfrag[2][4];
#pragma unroll
    for (int tt = 0; tt < 2; ++tt)
#pragma unroll
        for (int ks = 0; ks < 4; ++ks) {
            int tok = wid * 32 + tt * 16 + l15;
            bfrag[tt][ks] = *(const bf16x8*)(U + tok * 256 +
                (((unsigned)(ks * 64 + quad * 16)) ^ xorT));
        }
    __syncthreads();

    {
        const unsigned char* src = cbbq + (wid << 12) + (lane << 4);
        unsigned char* dst = U + (wid << 12) + (lane << 4);
        GLOAD_LDS16(src,        dst);
        GLOAD_LDS16(src + 1024, dst + 1024);
        GLOAD_LDS16(src + 2048, dst + 2048);
        GLOAD_LDS16(src + 3072, dst + 3072);
        if (lane < 16)
            GLOAD_LDS16((const unsigned char*)cnq + (lane << 4),
                        U + TRL + (lane << 4));
    }

    float rmin[2] = {1e30f, 1e30f};
    for (int cc = 0; cc < NCHUNKS; ++cc) {
        const int cur = cc & 1;
        __builtin_amdgcn_s_barrier();
        __builtin_amdgcn_sched_barrier(0);
        if (cc + 1 < NCHUNKS) {
            const unsigned char* src = cbbq + ((size_t)(cc + 1) << 14)
                                     + (wid << 12) + (lane << 4);
            unsigned char* dst = U + (cur ^ 1) * BUFSZ
                               + (wid << 12) + (lane << 4);
            GLOAD_LDS16(src,        dst);
            GLOAD_LDS16(src + 1024, dst + 1024);
            GLOAD_LDS16(src + 2048, dst + 2048);
            GLOAD_LDS16(src + 3072, dst + 3072);
            if (lane < 16)
                GLOAD_LDS16((const unsigned char*)(cnq + (cc + 1) * NCH)
                                + (lane << 4),
                            U + (cur ^ 1) * BUFSZ + TRL + (lane << 4));
            __builtin_amdgcn_sched_barrier(0);
            asm volatile("s_waitcnt vmcnt(5)" ::: "memory");
        } else {
            __builtin_amdgcn_sched_barrier(0);
            asm volatile("s_waitcnt vmcnt(0)" ::: "memory");
        }
        __builtin_amdgcn_s_barrier();
        __builtin_amdgcn_sched_barrier(0);

        f32x4 acc[4][2];
#pragma unroll
        for (int ct = 0; ct < 4; ++ct)
#pragma unroll
            for (int tt = 0; tt < 2; ++tt)
                acc[ct][tt] = (f32x4){0.f, 0.f, 0.f, 0.f};
        const unsigned char* Ub = U + cur * BUFSZ;
#pragma unroll
        for (int ks = 0; ks < 4; ++ks) {
            bf16x8 afr[4];
#pragma unroll
            for (int ct = 0; ct < 4; ++ct)
                afr[ct] = *(const bf16x8*)(Ub + (ct * 16 + l15) * 256 +
                    (((unsigned)(ks * 64 + quad * 16)) ^ xorT));
#pragma unroll
            for (int ct = 0; ct < 4; ++ct)
#pragma unroll
                for (int tt = 0; tt < 2; ++tt)
                    acc[ct][tt] = __builtin_amdgcn_mfma_f32_16x16x32_bf16(
                        afr[ct], bfrag[tt][ks], acc[ct][tt], 0, 0, 0);
        }

        const float* cnL = (const float*)(Ub + TRL);
        float tmin[2] = {1e30f, 1e30f};
#pragma unroll
        for (int ct = 0; ct < 4; ++ct) {
            f32x4 cn4 = *(const f32x4*)(cnL + ct * 16 + quad * 4);
#pragma unroll
            for (int tt = 0; tt < 2; ++tt)
#pragma unroll
                for (int r2 = 0; r2 < 4; ++r2) {
                    float m2 = acc[ct][tt][r2];
                    float e = cn4[r2] - (m2 + m2);
                    acc[ct][tt][r2] = e;
                    tmin[tt] = fminf(tmin[tt], e);
                }
        }
#pragma unroll
        for (int tt = 0; tt < 2; ++tt) {
            float v = tmin[tt];
            v = fminf(v, __shfl_xor(v, 16, 64));
            v = fminf(v, __shfl_xor(v, 32, 64));
            rmin[tt] = fminf(rmin[tt], v);
        }
#pragma unroll
        for (int tt = 0; tt < 2; ++tt) {
            int token = wid * 32 + tt * 16 + l15;
            float th = rmin[tt] + MARGIN;
#pragma unroll
            for (int ct = 0; ct < 4; ++ct)
#pragma unroll
                for (int r2 = 0; r2 < 4; ++r2) {
                    float e = acc[ct][tt][r2];
                    if (e <= th) {
                        int code = cc * NCH + ct * 16 + quad * 4 + r2;
                        int pos = atomicAdd(pairCnt, 1);
                        if (pos < PAIR_CAP)
                            pairList[pos] =
                                ((unsigned)token << 10) | (unsigned)code;
                    }
                }
        }
    }
    __syncthreads();

    {
        int npair = *pairCnt < PAIR_CAP ? *pairCnt : PAIR_CAP;
        for (int p = tid; p < npair; p += 256) {
            unsigned pk = pairList[p];
            int t = (pk >> 10) & 127, code = pk & 1023;
            const float* xr = x + (size_t)(t0 + t) * ED;
            const float* cr = cbq + (size_t)code * ED;
            const float* hp[Q > 0 ? Q : 1];
#pragma unroll
            for (int p2 = 0; p2 < Q; ++p2)
                hp[p2] = cb + ((size_t)p2 * KCB + (int)selSh[t * NQ + p2]) * ED;
            float M = 0.f;
#pragma unroll 4
            for (int k = 0; k < ED; k += 4) {
                float4 v = *(const float4*)(xr + k);
#pragma unroll
                for (int p2 = 0; p2 < Q; ++p2) {
                    float4 c = *(const float4*)(hp[p2] + k);
                    CHAIN4(v, c)
                }
                float4 cv = *(const float4*)(cr + k);
                M = fmaf(v.x, cv.x, M); M = fmaf(v.y, cv.y, M);
                M = fmaf(v.z, cv.z, M); M = fmaf(v.w, cv.w, M);
            }
            float t1 = Ss[t] - (M + M);
            float dd = t1 + cnorm[Q * KCB + code];
            unsigned long long key =
                ((unsigned long long)fmono(dd) << 10) | (unsigned)code;
            unsigned long long old = selMin[t];
            while (key < old) {
                unsigned long long assumed = old;
                old = atomicCAS(&selMin[t], assumed, key);
                if (old == assumed) break;
            }
        }
    }
    __syncthreads();

    if (tid < MT) {
        int code = (int)(selMin[tid] & 1023ull);
        selSh[tid * NQ + Q] = (unsigned short)code;
        d_out[(size_t)NT * ED + 1 + (size_t)(t0 + tid) * NQ + Q] = (float)code;
    }
    __syncthreads();
}

__global__ __launch_bounds__(256, 3) void rvq_mono(const float* __restrict__ x,
                                                   const float* __restrict__ cb,
                                                   const float* __restrict__ cnorm,
                                                   const unsigned char* __restrict__ cbb,
                                                   float* __restrict__ d_out) {
#pragma clang fp contract(off)
    __shared__ __align__(16) unsigned char U[2 * BUFSZ];
    __shared__ unsigned long long selMin[MT];
    __shared__ float    Ss[MT];
    __shared__ unsigned short selSh[MT * NQ];
    __shared__ unsigned pairList[PAIR_CAP];
    __shared__ int      pairCnt;
    __shared__ double   lossW[4];

    const int tid  = threadIdx.x;
    const int lane = tid & 63;
    const int wid  = tid >> 6;
    const int l15  = lane & 15;
    const int quad = lane >> 4;
    const int t0   = blockIdx.x * MT;
    const unsigned xorT = (unsigned)((l15 & 7) << 4);

    run_stage_mono<0>(x, cb, cnorm, cbb, d_out, U, selMin, Ss, selSh,
                      pairList, &pairCnt, tid, lane, wid, l15, quad, t0, xorT);
    run_stage_mono<1>(x, cb, cnorm, cbb, d_out, U, selMin, Ss, selSh,
                      pairList, &pairCnt, tid, lane, wid, l15, quad, t0, xorT);
    run_stage_mono<2>(x, cb, cnorm, cbb, d_out, U, selMin, Ss, selSh,
                      pairList, &pairCnt, tid, lane, wid, l15, quad, t0, xorT);
    run_stage_mono<3>(x, cb, cnorm, cbb, d_out, U, selMin, Ss, selSh,
                      pairList, &pairCnt, tid, lane, wid, l15, quad, t0, xorT);

    double lossTot = 0.0;
    if (tid < MT) {
        int t = tid;
        const float* xr = x + (size_t)(t0 + t) * ED;
        const float* hp[4];
#pragma unroll
        for (int p2 = 0; p2 < NQ; ++p2)
            hp[p2] = cb + ((size_t)p2 * KCB + (int)selSh[t * NQ + p2]) * ED;
        double lo = 0.0;
#pragma unroll 4
        for (int k = 0; k < ED; k += 4) {
            float4 v = *(const float4*)(xr + k);
            float4 o = v;
#pragma unroll
            for (int p2 = 0; p2 < NQ; ++p2) {
                float4 c = *(const float4*)(hp[p2] + k);
                CHAIN4(v, c)
                lo += (double)v.x * v.x + (double)v.y * v.y
                    + (double)v.z * v.z + (double)v.w * v.w;
            }
            float4 xq;
            xq.x = o.x - v.x; xq.y = o.y - v.y;
            xq.z = o.z - v.z; xq.w = o.w - v.w;
            *(float4*)(d_out + (size_t)(t0 + t) * ED + k) = xq;
        }
        lossTot = lo;
    }
    double l = lossTot;
#pragma unroll
    for (int off = 32; off > 0; off >>= 1) l += __shfl_down(l, off, 64);
    if ((tid & 63) == 0) lossW[tid >> 6] = l;
    __syncthreads();
    if (tid == 0) {
        double s = lossW[0] + lossW[1] + lossW[2] + lossW[3];
        atomicAdd(d_out + (size_t)NT * ED,
                  (float)(s * (0.25 / (4.0 * (double)NT * ED))));
    }
}

// ---------------------------------------------------------------------------
// workspace tiers:
//   full (>=66.6MB): cnorm 16K | cbb 1M | selG 1M | SsG 512K | rG 64M (MODE1)
//   mid  (>=36.2MB): cnorm 16K | cbb 1M | selG 1M | SsG 512K | As 32M (MODE0)
//   else: monolith
// ---------------------------------------------------------------------------
extern "C" void kernel_launch(void* const* d_in, const int* in_sizes, int n_in,
                              void* d_out, int out_size, void* d_ws, size_t ws_size,
                              hipStream_t stream) {
    const float* x  = (const float*)d_in[0];
    const float* cb = (const float*)d_in[1];
    float* out   = (float*)d_out;
    unsigned char* ws = (unsigned char*)d_ws;

    float* cnorm = (float*)ws;                                 // 16 KB
    unsigned char* cbb = ws + 16384;                           // 1 MiB
    unsigned short* selG = (unsigned short*)(ws + 16384 + (1u << 20));  // 1 MiB
    float* SsG = (float*)(ws + 16384 + (2u << 20));            // 512 KiB
    unsigned char* big = ws + 16384 + (2u << 20) + (1u << 19); // As or rG
    const size_t base = 16384 + (2ull << 20) + (1ull << 19);
    const size_t need_full = base + (64ull << 20);   // rG fp32
    const size_t need_mid  = base + (32ull << 20);   // As bf16

    prep_kernel<<<16, 256, 0, stream>>>(cb, cnorm, out + (size_t)NT * ED);
    cvt_kernel<<<256, 256, 0, stream>>>(cb, cbb);

    if (ws_size >= need_full) {
        float* rG = (float*)big;
        unsigned char* As = nullptr;
        s_kernel<0, 1><<<NT / 256, 256, 0, stream>>>(x, cb, selG, As, rG, SsG);
        select_kernel<0, 1><<<NBLK, 256, 0, stream>>>(x, cb, cnorm, cbb, As, rG, SsG, selG, out);
        s_kernel<1, 1><<<NT / 256, 256, 0, stream>>>(x, cb, selG, As, rG, SsG);
        select_kernel<1, 1><<<NBLK, 256, 0, stream>>>(x, cb, cnorm, cbb, As, rG, SsG, selG, out);
        s_kernel<2, 1><<<NT / 256, 256, 0, stream>>>(x, cb, selG, As, rG, SsG);
        select_kernel<2, 1><<<NBLK, 256, 0, stream>>>(x, cb, cnorm, cbb, As, rG, SsG, selG, out);
        s_kernel<3, 1><<<NT / 256, 256, 0, stream>>>(x, cb, selG, As, rG, SsG);
        select_kernel<3, 1><<<NBLK, 256, 0, stream>>>(x, cb, cnorm, cbb, As, rG, SsG, selG, out);
        epilogue_kernel<<<NT / 256, 256, 0, stream>>>(x, cb, selG, out);
    } else if (ws_size >= need_mid) {
        unsigned char* As = big;
        float* rG = nullptr;
        s_kernel<0, 0><<<NT / 256, 256, 0, stream>>>(x, cb, selG, As, rG, SsG);
        select_kernel<0, 0><<<NBLK, 256, 0, stream>>>(x, cb, cnorm, cbb, As, rG, SsG, selG, out);
        s_kernel<1, 0><<<NT / 256, 256, 0, stream>>>(x, cb, selG, As, rG, SsG);
        select_kernel<1, 0><<<NBLK, 256, 0, stream>>>(x, cb, cnorm, cbb, As, rG, SsG, selG, out);
        s_kernel<2, 0><<<NT / 256, 256, 0, stream>>>(x, cb, selG, As, rG, SsG);
        select_kernel<2, 0><<<NBLK, 256, 0, stream>>>(x, cb, cnorm, cbb, As, rG, SsG, selG, out);
        s_kernel<3, 0><<<NT / 256, 256, 0, stream>>>(x, cb, selG, As, rG, SsG);
        select_kernel<3, 0><<<NBLK, 256, 0, stream>>>(x, cb, cnorm, cbb, As, rG, SsG, selG, out);
        epilogue_kernel<<<NT / 256, 256, 0, stream>>>(x, cb, selG, out);
    } else {
        rvq_mono<<<NBLK, 256, 0, stream>>>(x, cb, cnorm, cbb, out);
    }
}

// Round 9
// 796.272 us; speedup vs baseline: 1.5798x; 1.1183x over previous
//
#include <hip/hip_runtime.h>

#define NT 131072
#define ED 128
#define KCB 1024
#define NQ 4

#define MT 128                 // tokens per select-block
#define NBLK (NT / MT)         // 1024 blocks
#define NCH 64                 // codes per chunk
#define NCHUNKS (KCB / NCH)    // 16
#define PAIR_CAP 1024
#define MARGIN 1.5e-3f

#define TRL 16384              // trailer (cnorm slice) offset inside a Bs buf
#define BUFSZ 16640            // 16 KB codes + 256 B cnorm trailer

typedef __attribute__((ext_vector_type(8))) short bf16x8;
typedef __attribute__((ext_vector_type(4))) float f32x4;

#define ASG __attribute__((address_space(1)))
#define ASL __attribute__((address_space(3)))
#define GLOAD_LDS16(g, l) \
    __builtin_amdgcn_global_load_lds((const ASG void*)(g), (ASL void*)(l), 16, 0, 0)

// ---- bf16 round-to-nearest-even, returns low 16 bits ----
__device__ __forceinline__ unsigned bf16rne(float f) {
    unsigned u = __float_as_uint(f);
    u += 0x7fffu + ((u >> 16) & 1u);
    return u >> 16;
}
__device__ __forceinline__ unsigned packbf(float a, float b) {
    return bf16rne(a) | (bf16rne(b) << 16);
}
// ---- monotone float->uint (unsigned compare preserves float order) ----
__device__ __forceinline__ unsigned fmono(float f) {
    unsigned u = __float_as_uint(f);
    return (u & 0x80000000u) ? ~u : (u | 0x80000000u);
}

// ---------------------------------------------------------------------------
// prep: cnorm[c] = np.sum(cb*cb, axis=1) fp32 numpy-pairwise (validated r3);
// zero the loss slot.
// ---------------------------------------------------------------------------
__global__ void prep_kernel(const float* __restrict__ cb,
                            float* __restrict__ cnorm,
                            float* __restrict__ loss_slot) {
#pragma clang fp contract(off)
    int c = blockIdx.x * 256 + threadIdx.x;   // 0..4095
    if (blockIdx.x == 0 && threadIdx.x == 0) loss_slot[0] = 0.0f;
    const float* row = cb + (size_t)c * ED;
    float r8[8];
#pragma unroll
    for (int m = 0; m < 8; ++m) { float v = row[m]; r8[m] = v * v; }
    for (int i = 8; i < ED; i += 8) {
#pragma unroll
        for (int m = 0; m < 8; ++m) {
            float v = row[i + m];
            float p = v * v;
            r8[m] = r8[m] + p;
        }
    }
    cnorm[c] = ((r8[0] + r8[1]) + (r8[2] + r8[3]))
             + ((r8[4] + r8[5]) + (r8[6] + r8[7]));
}

// ---------------------------------------------------------------------------
// cvt: codebooks -> bf16 swizzled chunk-linear image (r5-validated layout)
// for pure global_load_lds staging in the select kernel.
// ---------------------------------------------------------------------------
__global__ void cvt_kernel(const float* __restrict__ cb,
                           unsigned char* __restrict__ cbb) {
#pragma clang fp contract(off)
    int id = blockIdx.x * 256 + threadIdx.x;        // 0..65535
    int rg = id >> 4;                               // global code row 0..4095
    int j  = id & 15;                               // 16B block within row
    const float* src = cb + (size_t)rg * ED + j * 8;
    float4 a = *(const float4*)(src);
    float4 b = *(const float4*)(src + 4);
    uint4 w;
    w.x = packbf(a.x, a.y); w.y = packbf(a.z, a.w);
    w.z = packbf(b.x, b.y); w.w = packbf(b.z, b.w);
    size_t dst = ((size_t)(rg >> 6) << 14)          // 16 KiB chunk image
               + (size_t)((rg & 63) << 8)           // row * 256 B
               + (size_t)((j ^ (rg & 7)) << 4);     // swizzled 16B slot
    *(uint4*)(cbb + dst) = w;
}

// ---------------------------------------------------------------------------
// per-element straight-through chain step (validated r3)
#define CHAIN4(V, C)                                                     \
    { float d1x = (C).x - (V).x, d1y = (C).y - (V).y,                    \
            d1z = (C).z - (V).z, d1w = (C).w - (V).w;                    \
      float qtx = (V).x + d1x, qty = (V).y + d1y,                        \
            qtz = (V).z + d1z, qtw = (V).w + d1w;                        \
      (V).x = (V).x - qtx; (V).y = (V).y - qty;                          \
      (V).z = (V).z - qtz; (V).w = (V).w - qtw; }

// ---------------------------------------------------------------------------
// select_fused<Q>: GEMM-screen (r5-validated chunk loop) + exact rescore +
// selection + RESIDUAL-UPDATE TAIL (replaces the separate s_kernel).
//   rsrc = x (Q==0) else rG : exact fp32 residual of stage Q.
//   tail: r_{Q+1} = CHAIN4(r_Q, c_Q) per element -> rG, Ss_{Q+1} -> SsG.
// Chain identity: s_kernel's chain(chain(...(x,c0)..), cQ) == CHAIN4(rG, cQ)
// with rG holding the exact intermediate -> bit-identical floats.
// ---------------------------------------------------------------------------
template<int Q>
__global__ __launch_bounds__(256, 3) void select_fused(
    const float* __restrict__ x, const float* __restrict__ cb,
    const float* __restrict__ cnorm, const unsigned char* __restrict__ cbb,
    float* __restrict__ rG, float* __restrict__ SsG,
    unsigned short* __restrict__ selG, float* __restrict__ d_out) {
#pragma clang fp contract(off)
    __shared__ __align__(16) unsigned char U[2 * BUFSZ];   // Bs dbuf + trailers
    __shared__ unsigned long long selMin[MT];
    __shared__ float    SsL[MT];
    __shared__ unsigned pairList[PAIR_CAP];
    __shared__ int      pairCnt;

    const int tid  = threadIdx.x;
    const int lane = tid & 63;
    const int wid  = tid >> 6;     // wave 0..3 -> tokens [wid*32, wid*32+32)
    const int l15  = lane & 15;
    const int quad = lane >> 4;
    const int t0   = blockIdx.x * MT;
    const unsigned xorT = (unsigned)((l15 & 7) << 4);

    const float* cbq = cb + (size_t)Q * KCB * ED;
    const unsigned char* cbbq = cbb + ((size_t)Q << 18);  // Q*16 images
    const float* cnq = cnorm + Q * KCB;
    const float* rsrc = (Q == 0) ? x : rG;   // stage-Q residual source

    if (tid < MT) selMin[tid] = ~0ull;
    if (tid == 0) pairCnt = 0;

    // ---- Ss for stage Q into LDS ----
    if (Q == 0) {
        // Ss0 = ||x||^2, numpy 8-acc pairwise (identical to validated S-phase)
        if (tid < MT) {
            const float* xr = x + (size_t)(t0 + tid) * ED;
            float r8[8];
#pragma unroll
            for (int m = 0; m < 8; ++m) r8[m] = 0.f;
#pragma unroll 4
            for (int i = 0; i < 32; ++i) {
                float4 v = *(const float4*)(xr + (i << 2));
                int base = (i & 1) << 2;
                float px = v.x * v.x, py = v.y * v.y,
                      pz = v.z * v.z, pw = v.w * v.w;
                r8[base + 0] = r8[base + 0] + px;
                r8[base + 1] = r8[base + 1] + py;
                r8[base + 2] = r8[base + 2] + pz;
                r8[base + 3] = r8[base + 3] + pw;
            }
            SsL[tid] = ((r8[0] + r8[1]) + (r8[2] + r8[3]))
                     + ((r8[4] + r8[5]) + (r8[6] + r8[7]));
        }
    } else {
        if (tid < MT) SsL[tid] = SsG[t0 + tid];   // written by prev tail
    }
    __syncthreads();

    // ---- token (B-operand) fragments: pack bf16 from rsrc in-register ----
    bf16x8 bfrag[2][4];
#pragma unroll
    for (int tt = 0; tt < 2; ++tt)
#pragma unroll
        for (int ks = 0; ks < 4; ++ks) {
            int tok = t0 + wid * 32 + tt * 16 + l15;
            const float* rr = rsrc + (size_t)tok * ED + ks * 32 + quad * 8;
            float4 a = *(const float4*)(rr);
            float4 b = *(const float4*)(rr + 4);
            uint4 w;
            w.x = packbf(a.x, a.y); w.y = packbf(a.z, a.w);
            w.z = packbf(b.x, b.y); w.w = packbf(b.z, b.w);
            bfrag[tt][ks] = __builtin_bit_cast(bf16x8, w);
        }

    // ---- stage chunk 0 into buf 0: 4 code DMAs + 1 cnorm-trailer DMA ----
    {
        const unsigned char* src = cbbq + (wid << 12) + (lane << 4);
        unsigned char* dst = U + (wid << 12) + (lane << 4);
        GLOAD_LDS16(src,        dst);
        GLOAD_LDS16(src + 1024, dst + 1024);
        GLOAD_LDS16(src + 2048, dst + 2048);
        GLOAD_LDS16(src + 3072, dst + 3072);
        if (lane < 16)
            GLOAD_LDS16((const unsigned char*)cnq + (lane << 4),
                        U + TRL + (lane << 4));
    }

    // ---- chunk loop: double-buffered Bs, counted-vmcnt pipeline ----
    float rmin[2] = {1e30f, 1e30f};   // per-token running min (wave-private)
    for (int cc = 0; cc < NCHUNKS; ++cc) {
        const int cur = cc & 1;

        __builtin_amdgcn_s_barrier();
        __builtin_amdgcn_sched_barrier(0);

        if (cc + 1 < NCHUNKS) {
            const unsigned char* src = cbbq + ((size_t)(cc + 1) << 14)
                                     + (wid << 12) + (lane << 4);
            unsigned char* dst = U + (cur ^ 1) * BUFSZ
                               + (wid << 12) + (lane << 4);
            GLOAD_LDS16(src,        dst);
            GLOAD_LDS16(src + 1024, dst + 1024);
            GLOAD_LDS16(src + 2048, dst + 2048);
            GLOAD_LDS16(src + 3072, dst + 3072);
            if (lane < 16)
                GLOAD_LDS16((const unsigned char*)(cnq + (cc + 1) * NCH)
                                + (lane << 4),
                            U + (cur ^ 1) * BUFSZ + TRL + (lane << 4));
            __builtin_amdgcn_sched_barrier(0);
            asm volatile("s_waitcnt vmcnt(5)" ::: "memory");
        } else {
            __builtin_amdgcn_sched_barrier(0);
            asm volatile("s_waitcnt vmcnt(0)" ::: "memory");
        }
        __builtin_amdgcn_s_barrier();
        __builtin_amdgcn_sched_barrier(0);

        // MFMA: D[code][token] over 64 codes x 32 tokens per wave
        f32x4 acc[4][2];
#pragma unroll
        for (int ct = 0; ct < 4; ++ct)
#pragma unroll
            for (int tt = 0; tt < 2; ++tt)
                acc[ct][tt] = (f32x4){0.f, 0.f, 0.f, 0.f};
        const unsigned char* Ub = U + cur * BUFSZ;
#pragma unroll
        for (int ks = 0; ks < 4; ++ks) {
            bf16x8 afr[4];
#pragma unroll
            for (int ct = 0; ct < 4; ++ct)
                afr[ct] = *(const bf16x8*)(Ub + (ct * 16 + l15) * 256 +
                    (((unsigned)(ks * 64 + quad * 16)) ^ xorT));
#pragma unroll
            for (int ct = 0; ct < 4; ++ct)
#pragma unroll
                for (int tt = 0; tt < 2; ++tt)
                    acc[ct][tt] = __builtin_amdgcn_mfma_f32_16x16x32_bf16(
                        afr[ct], bfrag[tt][ks], acc[ct][tt], 0, 0, 0);
        }

        // scores e = cn - 2*M~ (approx; exact handled by rescore) + min
        const float* cnL = (const float*)(Ub + TRL);
        float tmin[2] = {1e30f, 1e30f};
#pragma unroll
        for (int ct = 0; ct < 4; ++ct) {
            f32x4 cn4 = *(const f32x4*)(cnL + ct * 16 + quad * 4);
#pragma unroll
            for (int tt = 0; tt < 2; ++tt)
#pragma unroll
                for (int r2 = 0; r2 < 4; ++r2) {
                    float m2 = acc[ct][tt][r2];
                    float e = cn4[r2] - (m2 + m2);
                    acc[ct][tt][r2] = e;
                    tmin[tt] = fminf(tmin[tt], e);
                }
        }
#pragma unroll
        for (int tt = 0; tt < 2; ++tt) {
            float v = tmin[tt];
            v = fminf(v, __shfl_xor(v, 16, 64));
            v = fminf(v, __shfl_xor(v, 32, 64));
            rmin[tt] = fminf(rmin[tt], v);
        }

        // candidate pass for THIS chunk (threshold incl. own chunk)
#pragma unroll
        for (int tt = 0; tt < 2; ++tt) {
            int token = wid * 32 + tt * 16 + l15;
            float th = rmin[tt] + MARGIN;
#pragma unroll
            for (int ct = 0; ct < 4; ++ct)
#pragma unroll
                for (int r2 = 0; r2 < 4; ++r2) {
                    float e = acc[ct][tt][r2];
                    if (e <= th) {
                        int code = cc * NCH + ct * 16 + quad * 4 + r2;
                        int pos = atomicAdd(&pairCnt, 1);
                        if (pos < PAIR_CAP)
                            pairList[pos] =
                                ((unsigned)token << 10) | (unsigned)code;
                    }
                }
        }
    }
    __syncthreads();   // all candidate pushes visible

    // ---- exact rescore of candidates (M chain fmaf-order-identical) ----
    {
        int npair = pairCnt < PAIR_CAP ? pairCnt : PAIR_CAP;
        for (int p = tid; p < npair; p += 256) {
            unsigned pk = pairList[p];
            int t = (pk >> 10) & 127, code = pk & 1023;
            const float* cr = cbq + (size_t)code * ED;
            const float* rr = rsrc + (size_t)(t0 + t) * ED;
            float M = 0.f;
#pragma unroll 4
            for (int k = 0; k < ED; k += 4) {
                float4 v = *(const float4*)(rr + k);
                float4 cv = *(const float4*)(cr + k);
                M = fmaf(v.x, cv.x, M); M = fmaf(v.y, cv.y, M);
                M = fmaf(v.z, cv.z, M); M = fmaf(v.w, cv.w, M);
            }
            float t1 = SsL[t] - (M + M);            // rounded (contract off)
            float dd = t1 + cnorm[Q * KCB + code];  // rounded
            unsigned long long key =
                ((unsigned long long)fmono(dd) << 10) | (unsigned)code;
            unsigned long long old = selMin[t];
            while (key < old) {
                unsigned long long assumed = old;
                old = atomicCAS(&selMin[t], assumed, key);
                if (old == assumed) break;
            }
        }
    }
    __syncthreads();   // rescore done; all rsrc-row reads complete

    // ---- selection write + residual-update tail (replaces s_kernel) ----
    if (tid < MT) {
        int t = tid;
        int code = (int)(selMin[t] & 1023ull);
        selG[(size_t)(t0 + t) * NQ + Q] = (unsigned short)code;
        d_out[(size_t)NT * ED + 1 + (size_t)(t0 + t) * NQ + Q] = (float)code;

        if (Q < NQ - 1) {
            const float* rr = rsrc + (size_t)(t0 + t) * ED;
            const float* cr = cbq + (size_t)code * ED;
            float* rw = rG + (size_t)(t0 + t) * ED;
            float r8[8];
#pragma unroll
            for (int m = 0; m < 8; ++m) r8[m] = 0.f;
#pragma unroll 4
            for (int i = 0; i < 32; ++i) {
                float4 v = *(const float4*)(rr + (i << 2));
                float4 c = *(const float4*)(cr + (i << 2));
                CHAIN4(v, c)
                *(float4*)(rw + (i << 2)) = v;      // exact fp32 r_{Q+1}
                int base = (i & 1) << 2;
                float px = v.x * v.x, py = v.y * v.y,
                      pz = v.z * v.z, pw = v.w * v.w;
                r8[base + 0] = r8[base + 0] + px;
                r8[base + 1] = r8[base + 1] + py;
                r8[base + 2] = r8[base + 2] + pz;
                r8[base + 3] = r8[base + 3] + pw;
            }
            SsG[t0 + t] = ((r8[0] + r8[1]) + (r8[2] + r8[3]))
                        + ((r8[4] + r8[5]) + (r8[6] + r8[7]));
        }
    }
}

// ---------------------------------------------------------------------------
// epilogue_kernel: x_q = x - r4 (exact chain) + loss. One thread per token.
// (unchanged: double-accumulation order preserved for bit-stability)
// ---------------------------------------------------------------------------
__global__ void epilogue_kernel(const float* __restrict__ x,
                                const float* __restrict__ cb,
                                const unsigned short* __restrict__ selG,
                                float* __restrict__ d_out) {
#pragma clang fp contract(off)
    __shared__ double lossW[4];
    int tid = threadIdx.x;
    int t = blockIdx.x * 256 + tid;
    const float* xr = x + (size_t)t * ED;
    const float* hp[4];
#pragma unroll
    for (int p2 = 0; p2 < NQ; ++p2)
        hp[p2] = cb + ((size_t)p2 * KCB + (int)selG[t * NQ + p2]) * ED;
    double lo = 0.0;
#pragma unroll 4
    for (int k = 0; k < ED; k += 4) {
        float4 v = *(const float4*)(xr + k);
        float4 o = v;
#pragma unroll
        for (int p2 = 0; p2 < NQ; ++p2) {
            float4 c = *(const float4*)(hp[p2] + k);
            CHAIN4(v, c)
            lo += (double)v.x * v.x + (double)v.y * v.y
                + (double)v.z * v.z + (double)v.w * v.w;
        }
        float4 xq;
        xq.x = o.x - v.x; xq.y = o.y - v.y;
        xq.z = o.z - v.z; xq.w = o.w - v.w;
        *(float4*)(d_out + (size_t)t * ED + k) = xq;
    }
#pragma unroll
    for (int off = 32; off > 0; off >>= 1) lo += __shfl_down(lo, off, 64);
    if ((tid & 63) == 0) lossW[tid >> 6] = lo;
    __syncthreads();
    if (tid == 0) {
        double s = lossW[0] + lossW[1] + lossW[2] + lossW[3];
        atomicAdd(d_out + (size_t)NT * ED,
                  (float)(s * (0.25 / (4.0 * (double)NT * ED))));
    }
}

// ===========================================================================
// FALLBACK MONOLITH (r5-validated, used when workspace is tiny)
// ===========================================================================
template<int Q>
__device__ __forceinline__ void run_stage_mono(
    const float* __restrict__ x, const float* __restrict__ cb,
    const float* __restrict__ cnorm, const unsigned char* __restrict__ cbb,
    float* __restrict__ d_out,
    unsigned char* U, unsigned long long* selMin, float* Ss,
    unsigned short* selSh, unsigned* pairList, int* pairCnt,
    int tid, int lane, int wid, int l15, int quad, int t0, unsigned xorT) {
#pragma clang fp contract(off)
    const float* cbq = cb + (size_t)Q * KCB * ED;
    const unsigned char* cbbq = cbb + ((size_t)Q << 18);
    const float* cnq = cnorm + Q * KCB;

    if (tid < MT) selMin[tid] = ~0ull;
    if (tid == 0) *pairCnt = 0;
    __syncthreads();

    if (tid < MT) {
        int t = tid;
        const float* xr = x + (size_t)(t0 + t) * ED;
        const float* hp[Q > 0 ? Q : 1];
#pragma unroll
        for (int p2 = 0; p2 < Q; ++p2)
            hp[p2] = cb + ((size_t)p2 * KCB + (int)selSh[t * NQ + p2]) * ED;
        unsigned char* Aw = U + t * 256;
        unsigned xw = (unsigned)((t & 7) << 4);
        float r8[8];
#pragma unroll
        for (int m = 0; m < 8; ++m) r8[m] = 0.f;
#pragma unroll 4
        for (int i = 0; i < 32; ++i) {
            float4 v = *(const float4*)(xr + (i << 2));
#pragma unroll
            for (int p2 = 0; p2 < Q; ++p2) {
                float4 c = *(const float4*)(hp[p2] + (i << 2));
                CHAIN4(v, c)
            }
            uint2 w2;
            w2.x = packbf(v.x, v.y); w2.y = packbf(v.z, v.w);
            *(uint2*)(Aw + (((((unsigned)(i >> 1)) << 4) ^ xw)
                            | ((unsigned)(i & 1) << 3))) = w2;
            int base = (i & 1) << 2;
            float px = v.x * v.x, py = v.y * v.y,
                  pz = v.z * v.z, pw = v.w * v.w;
            r8[base + 0] = r8[base + 0] + px;
            r8[base + 1] = r8[base + 1] + py;
            r8[base + 2] = r8[base + 2] + pz;
            r8[base + 3] = r8[base + 3] + pw;
        }
        Ss[t] = ((r8[0] + r8[1]) + (r8[2] + r8[3]))
              + ((r8[4] + r8[5]) + (r8[6] + r8[7]));
    }
    __syncthreads();

    bf16x8 bfrag[2][4];
#pragma unroll
    for (int tt = 0; tt < 2; ++tt)
#pragma unroll
        for (int ks = 0; ks < 4; ++ks) {
            int tok = wid * 32 + tt * 16 + l15;
            bfrag[tt][ks] = *(const bf16x8*)(U + tok * 256 +
                (((unsigned)(ks * 64 + quad * 16)) ^ xorT));
        }
    __syncthreads();

    {
        const unsigned char* src = cbbq + (wid << 12) + (lane << 4);
        unsigned char* dst = U + (wid << 12) + (lane << 4);
        GLOAD_LDS16(src,        dst);
        GLOAD_LDS16(src + 1024, dst + 1024);
        GLOAD_LDS16(src + 2048, dst + 2048);
        GLOAD_LDS16(src + 3072, dst + 3072);
        if (lane < 16)
            GLOAD_LDS16((const unsigned char*)cnq + (lane << 4),
                        U + TRL + (lane << 4));
    }

    float rmin[2] = {1e30f, 1e30f};
    for (int cc = 0; cc < NCHUNKS; ++cc) {
        const int cur = cc & 1;
        __builtin_amdgcn_s_barrier();
        __builtin_amdgcn_sched_barrier(0);
        if (cc + 1 < NCHUNKS) {
            const unsigned char* src = cbbq + ((size_t)(cc + 1) << 14)
                                     + (wid << 12) + (lane << 4);
            unsigned char* dst = U + (cur ^ 1) * BUFSZ
                               + (wid << 12) + (lane << 4);
            GLOAD_LDS16(src,        dst);
            GLOAD_LDS16(src + 1024, dst + 1024);
            GLOAD_LDS16(src + 2048, dst + 2048);
            GLOAD_LDS16(src + 3072, dst + 3072);
            if (lane < 16)
                GLOAD_LDS16((const unsigned char*)(cnq + (cc + 1) * NCH)
                                + (lane << 4),
                            U + (cur ^ 1) * BUFSZ + TRL + (lane << 4));
            __builtin_amdgcn_sched_barrier(0);
            asm volatile("s_waitcnt vmcnt(5)" ::: "memory");
        } else {
            __builtin_amdgcn_sched_barrier(0);
            asm volatile("s_waitcnt vmcnt(0)" ::: "memory");
        }
        __builtin_amdgcn_s_barrier();
        __builtin_amdgcn_sched_barrier(0);

        f32x4 acc[4][2];
#pragma unroll
        for (int ct = 0; ct < 4; ++ct)
#pragma unroll
            for (int tt = 0; tt < 2; ++tt)
                acc[ct][tt] = (f32x4){0.f, 0.f, 0.f, 0.f};
        const unsigned char* Ub = U + cur * BUFSZ;
#pragma unroll
        for (int ks = 0; ks < 4; ++ks) {
            bf16x8 afr[4];
#pragma unroll
            for (int ct = 0; ct < 4; ++ct)
                afr[ct] = *(const bf16x8*)(Ub + (ct * 16 + l15) * 256 +
                    (((unsigned)(ks * 64 + quad * 16)) ^ xorT));
#pragma unroll
            for (int ct = 0; ct < 4; ++ct)
#pragma unroll
                for (int tt = 0; tt < 2; ++tt)
                    acc[ct][tt] = __builtin_amdgcn_mfma_f32_16x16x32_bf16(
                        afr[ct], bfrag[tt][ks], acc[ct][tt], 0, 0, 0);
        }

        const float* cnL = (const float*)(Ub + TRL);
        float tmin[2] = {1e30f, 1e30f};
#pragma unroll
        for (int ct = 0; ct < 4; ++ct) {
            f32x4 cn4 = *(const f32x4*)(cnL + ct * 16 + quad * 4);
#pragma unroll
            for (int tt = 0; tt < 2; ++tt)
#pragma unroll
                for (int r2 = 0; r2 < 4; ++r2) {
                    float m2 = acc[ct][tt][r2];
                    float e = cn4[r2] - (m2 + m2);
                    acc[ct][tt][r2] = e;
                    tmin[tt] = fminf(tmin[tt], e);
                }
        }
#pragma unroll
        for (int tt = 0; tt < 2; ++tt) {
            float v = tmin[tt];
            v = fminf(v, __shfl_xor(v, 16, 64));
            v = fminf(v, __shfl_xor(v, 32, 64));
            rmin[tt] = fminf(rmin[tt], v);
        }
#pragma unroll
        for (int tt = 0; tt < 2; ++tt) {
            int token = wid * 32 + tt * 16 + l15;
            float th = rmin[tt] + MARGIN;
#pragma unroll
            for (int ct = 0; ct < 4; ++ct)
#pragma unroll
                for (int r2 = 0; r2 < 4; ++r2) {
                    float e = acc[ct][tt][r2];
                    if (e <= th) {
                        int code = cc * NCH + ct * 16 + quad * 4 + r2;
                        int pos = atomicAdd(pairCnt, 1);
                        if (pos < PAIR_CAP)
                            pairList[pos] =
                                ((unsigned)token << 10) | (unsigned)code;
                    }
                }
        }
    }
    __syncthreads();

    {
        int npair = *pairCnt < PAIR_CAP ? *pairCnt : PAIR_CAP;
        for (int p = tid; p < npair; p += 256) {
            unsigned pk = pairList[p];
            int t = (pk >> 10) & 127, code = pk & 1023;
            const float* xr = x + (size_t)(t0 + t) * ED;
            const float* cr = cbq + (size_t)code * ED;
            const float* hp[Q > 0 ? Q : 1];
#pragma unroll
            for (int p2 = 0; p2 < Q; ++p2)
                hp[p2] = cb + ((size_t)p2 * KCB + (int)selSh[t * NQ + p2]) * ED;
            float M = 0.f;
#pragma unroll 4
            for (int k = 0; k < ED; k += 4) {
                float4 v = *(const float4*)(xr + k);
#pragma unroll
                for (int p2 = 0; p2 < Q; ++p2) {
                    float4 c = *(const float4*)(hp[p2] + k);
                    CHAIN4(v, c)
                }
                float4 cv = *(const float4*)(cr + k);
                M = fmaf(v.x, cv.x, M); M = fmaf(v.y, cv.y, M);
                M = fmaf(v.z, cv.z, M); M = fmaf(v.w, cv.w, M);
            }
            float t1 = Ss[t] - (M + M);
            float dd = t1 + cnorm[Q * KCB + code];
            unsigned long long key =
                ((unsigned long long)fmono(dd) << 10) | (unsigned)code;
            unsigned long long old = selMin[t];
            while (key < old) {
                unsigned long long assumed = old;
                old = atomicCAS(&selMin[t], assumed, key);
                if (old == assumed) break;
            }
        }
    }
    __syncthreads();

    if (tid < MT) {
        int code = (int)(selMin[tid] & 1023ull);
        selSh[tid * NQ + Q] = (unsigned short)code;
        d_out[(size_t)NT * ED + 1 + (size_t)(t0 + tid) * NQ + Q] = (float)code;
    }
    __syncthreads();
}

__global__ __launch_bounds__(256, 3) void rvq_mono(const float* __restrict__ x,
                                                   const float* __restrict__ cb,
                                                   const float* __restrict__ cnorm,
                                                   const unsigned char* __restrict__ cbb,
                                                   float* __restrict__ d_out) {
#pragma clang fp contract(off)
    __shared__ __align__(16) unsigned char U[2 * BUFSZ];
    __shared__ unsigned long long selMin[MT];
    __shared__ float    Ss[MT];
    __shared__ unsigned short selSh[MT * NQ];
    __shared__ unsigned pairList[PAIR_CAP];
    __shared__ int      pairCnt;
    __shared__ double   lossW[4];

    const int tid  = threadIdx.x;
    const int lane = tid & 63;
    const int wid  = tid >> 6;
    const int l15  = lane & 15;
    const int quad = lane >> 4;
    const int t0   = blockIdx.x * MT;
    const unsigned xorT = (unsigned)((l15 & 7) << 4);

    run_stage_mono<0>(x, cb, cnorm, cbb, d_out, U, selMin, Ss, selSh,
                      pairList, &pairCnt, tid, lane, wid, l15, quad, t0, xorT);
    run_stage_mono<1>(x, cb, cnorm, cbb, d_out, U, selMin, Ss, selSh,
                      pairList, &pairCnt, tid, lane, wid, l15, quad, t0, xorT);
    run_stage_mono<2>(x, cb, cnorm, cbb, d_out, U, selMin, Ss, selSh,
                      pairList, &pairCnt, tid, lane, wid, l15, quad, t0, xorT);
    run_stage_mono<3>(x, cb, cnorm, cbb, d_out, U, selMin, Ss, selSh,
                      pairList, &pairCnt, tid, lane, wid, l15, quad, t0, xorT);

    double lossTot = 0.0;
    if (tid < MT) {
        int t = tid;
        const float* xr = x + (size_t)(t0 + t) * ED;
        const float* hp[4];
#pragma unroll
        for (int p2 = 0; p2 < NQ; ++p2)
            hp[p2] = cb + ((size_t)p2 * KCB + (int)selSh[t * NQ + p2]) * ED;
        double lo = 0.0;
#pragma unroll 4
        for (int k = 0; k < ED; k += 4) {
            float4 v = *(const float4*)(xr + k);
            float4 o = v;
#pragma unroll
            for (int p2 = 0; p2 < NQ; ++p2) {
                float4 c = *(const float4*)(hp[p2] + k);
                CHAIN4(v, c)
                lo += (double)v.x * v.x + (double)v.y * v.y
                    + (double)v.z * v.z + (double)v.w * v.w;
            }
            float4 xq;
            xq.x = o.x - v.x; xq.y = o.y - v.y;
            xq.z = o.z - v.z; xq.w = o.w - v.w;
            *(float4*)(d_out + (size_t)(t0 + t) * ED + k) = xq;
        }
        lossTot = lo;
    }
    double l = lossTot;
#pragma unroll
    for (int off = 32; off > 0; off >>= 1) l += __shfl_down(l, off, 64);
    if ((tid & 63) == 0) lossW[tid >> 6] = l;
    __syncthreads();
    if (tid == 0) {
        double s = lossW[0] + lossW[1] + lossW[2] + lossW[3];
        atomicAdd(d_out + (size_t)NT * ED,
                  (float)(s * (0.25 / (4.0 * (double)NT * ED))));
    }
}

// ---------------------------------------------------------------------------
// workspace: cnorm 16K | cbb 1M | selG 1M | SsG 512K | rG 64M  (~66.6 MB)
// falls back to monolith when ws too small.
// ---------------------------------------------------------------------------
extern "C" void kernel_launch(void* const* d_in, const int* in_sizes, int n_in,
                              void* d_out, int out_size, void* d_ws, size_t ws_size,
                              hipStream_t stream) {
    const float* x  = (const float*)d_in[0];
    const float* cb = (const float*)d_in[1];
    float* out   = (float*)d_out;
    unsigned char* ws = (unsigned char*)d_ws;

    float* cnorm = (float*)ws;                                 // 16 KB
    unsigned char* cbb = ws + 16384;                           // 1 MiB
    unsigned short* selG = (unsigned short*)(ws + 16384 + (1u << 20));  // 1 MiB
    float* SsG = (float*)(ws + 16384 + (2u << 20));            // 512 KiB
    float* rG  = (float*)(ws + 16384 + (2u << 20) + (1u << 19)); // 64 MiB
    const size_t need = 16384 + (2ull << 20) + (1ull << 19) + (64ull << 20);

    prep_kernel<<<16, 256, 0, stream>>>(cb, cnorm, out + (size_t)NT * ED);
    cvt_kernel<<<256, 256, 0, stream>>>(cb, cbb);

    if (ws_size >= need) {
        select_fused<0><<<NBLK, 256, 0, stream>>>(x, cb, cnorm, cbb, rG, SsG, selG, out);
        select_fused<1><<<NBLK, 256, 0, stream>>>(x, cb, cnorm, cbb, rG, SsG, selG, out);
        select_fused<2><<<NBLK, 256, 0, stream>>>(x, cb, cnorm, cbb, rG, SsG, selG, out);
        select_fused<3><<<NBLK, 256, 0, stream>>>(x, cb, cnorm, cbb, rG, SsG, selG, out);
        epilogue_kernel<<<NT / 256, 256, 0, stream>>>(x, cb, selG, out);
    } else {
        rvq_mono<<<NBLK, 256, 0, stream>>>(x, cb, cnorm, cbb, out);
    }
}